// Round 6
// baseline (192.402 us; speedup 1.0000x reference)
//
#include <hip/hip_runtime.h>
#include <hip/hip_bf16.h>
#include <hip/hip_fp16.h>
#include <math.h>

// ---------------------------------------------------------------------------
// GCN 2-layer, CSR-gather formulation, fp16 intermediate storage:
//   rank[e] = atomicAdd(degi[dst[e]],1)      (histogram + rank in one pass)
//   rowstart = exscan(degi); dinv = rsqrt(degi+1)
//   csr[rowstart[t] + rank[e]] = (src, dinv[s]*dinv[t])   (atomic-free fill)
//   h1(fp16) = x @ W1;  out1(fp16) = relu(gather(h1) + self + b1)
//   agg2(fp16) = gather(out1) + self     (linearity: aggregate BEFORE gemm2)
//   out = log_softmax(agg2 @ W2 + b2)    (softmax fused into gemm2 epilogue)
// ---------------------------------------------------------------------------

__global__ void zero_kernel(int* __restrict__ p, int n) {
    int i = blockIdx.x * blockDim.x + threadIdx.x;
    if (i < n) p[i] = 0;
}

__global__ void deg_rank_kernel(const int* __restrict__ dst, int* __restrict__ degi,
                                int* __restrict__ rank, int E) {
    int i = blockIdx.x * blockDim.x + threadIdx.x;
    if (i < E) rank[i] = atomicAdd(&degi[dst[i]], 1);
}

// ---- block sums of degi (1024 items / block) ----
__global__ __launch_bounds__(256) void blocksum_kernel(const int* __restrict__ degi,
                                                       int* __restrict__ partial, int n) {
    __shared__ int sm[256];
    int t = threadIdx.x;
    int base = blockIdx.x * 1024 + t * 4;
    int s = 0;
#pragma unroll
    for (int j = 0; j < 4; ++j) { int i = base + j; if (i < n) s += degi[i]; }
    sm[t] = s;
    __syncthreads();
    for (int off = 128; off > 0; off >>= 1) {
        if (t < off) sm[t] += sm[t + off];
        __syncthreads();
    }
    if (t == 0) partial[blockIdx.x] = sm[0];
}

// rowstart = exscan(degi); partial-scan fused (each block scans all partials);
// also degi <- rsqrt(degi+1) in place (dinv)
__global__ __launch_bounds__(256) void offsets_kernel(int* __restrict__ degi,
                                                      const int* __restrict__ partial,
                                                      int* __restrict__ rowstart,
                                                      int n, int nb) {
    __shared__ int sm[256];
    __shared__ int pbase_s;
    int t = threadIdx.x;
    // scan the block partials (nb <= 256) locally
    int pv = (t < nb) ? partial[t] : 0;
    sm[t] = pv;
    __syncthreads();
    for (int off = 1; off < 256; off <<= 1) {
        int x = (t >= off) ? sm[t - off] : 0;
        __syncthreads();
        sm[t] += x;
        __syncthreads();
    }
    if (t == 0) pbase_s = (blockIdx.x > 0) ? sm[blockIdx.x - 1] : 0;
    __syncthreads();
    int pbase = pbase_s;
    __syncthreads();   // sm about to be reused

    int base = blockIdx.x * 1024 + t * 4;
    int v[4]; int s = 0;
#pragma unroll
    for (int j = 0; j < 4; ++j) { v[j] = (base + j < n) ? degi[base + j] : 0; s += v[j]; }
    sm[t] = s;
    __syncthreads();
    for (int off = 1; off < 256; off <<= 1) {
        int x = (t >= off) ? sm[t - off] : 0;
        __syncthreads();
        sm[t] += x;
        __syncthreads();
    }
    int run = pbase + (sm[t] - s);
#pragma unroll
    for (int j = 0; j < 4; ++j) {
        if (base + j < n) {
            rowstart[base + j] = run; run += v[j];
            ((float*)degi)[base + j] = rsqrtf((float)v[j] + 1.0f);  // +1 self-loop
        }
    }
}

// atomic-free fill: pos = rowstart[t] + rank[e]
__global__ void fill_kernel(const int* __restrict__ src, const int* __restrict__ dst,
                            const int* __restrict__ rank, const float* __restrict__ dinv,
                            const int* __restrict__ rowstart, int2* __restrict__ csr, int E) {
    int e = blockIdx.x * blockDim.x + threadIdx.x;
    if (e >= E) return;
    int s = src[e], t = dst[e];
    float nrm = dinv[s] * dinv[t];
    int pos = rowstart[t] + rank[e];
    csr[pos] = make_int2(s, __float_as_int(nrm));
}

// ---- GEMM1: H[n,64](fp16) = X[n,128] @ W[128,64], 4x4 regs/thread ----
template <int K, int C, int BM>
__global__ __launch_bounds__(256) void gemm_tiled_h(const float* __restrict__ X,
                                                    const float* __restrict__ W,
                                                    __half* __restrict__ H, int n) {
    constexpr int BK = 32;
    constexpr int XP = 36;
    constexpr int ROWG = BM / 4;
    constexpr int COLG = C / 4;
    __shared__ float Xs[BM][XP];
    __shared__ float Ws[BK][C];
    int t = threadIdx.x;
    int tx = t % COLG;
    int ty = t / COLG;
    bool active = ty < ROWG;
    int rowbase = blockIdx.x * BM;
    float acc[4][4] = {};

    for (int kc = 0; kc < K; kc += BK) {
        for (int fi = t; fi < BM * 8; fi += 256) {
            int row = fi >> 3, kq = fi & 7;
            int gr = rowbase + row; if (gr >= n) gr = n - 1;
            float4 v = *reinterpret_cast<const float4*>(X + (size_t)gr * K + kc + kq * 4);
            *reinterpret_cast<float4*>(&Xs[row][kq * 4]) = v;
        }
        for (int fi = t; fi < BK * C / 4; fi += 256) {
            reinterpret_cast<float4*>(&Ws[0][0])[fi] =
                reinterpret_cast<const float4*>(W + (size_t)kc * C)[fi];
        }
        __syncthreads();
        if (active) {
#pragma unroll
            for (int k0 = 0; k0 < BK; k0 += 4) {
                float4 xq[4], wq[4];
#pragma unroll
                for (int i = 0; i < 4; ++i)
                    xq[i] = *reinterpret_cast<const float4*>(&Xs[ty * 4 + i][k0]);
#pragma unroll
                for (int j = 0; j < 4; ++j)
                    wq[j] = *reinterpret_cast<const float4*>(&Ws[k0 + j][tx * 4]);
#pragma unroll
                for (int i = 0; i < 4; ++i) {
                    const float* xa = reinterpret_cast<const float*>(&xq[i]);
#pragma unroll
                    for (int j = 0; j < 4; ++j) {
                        const float* wb = reinterpret_cast<const float*>(&wq[j]);
                        acc[i][0] += xa[j] * wb[0];
                        acc[i][1] += xa[j] * wb[1];
                        acc[i][2] += xa[j] * wb[2];
                        acc[i][3] += xa[j] * wb[3];
                    }
                }
            }
        }
        __syncthreads();
    }
    if (active) {
#pragma unroll
        for (int i = 0; i < 4; ++i) {
            int gr = rowbase + ty * 4 + i;
            if (gr < n) {
                __half2 h0 = __float22half2_rn(make_float2(acc[i][0], acc[i][1]));
                __half2 h1 = __float22half2_rn(make_float2(acc[i][2], acc[i][3]));
                uint2 u;
                u.x = *reinterpret_cast<unsigned int*>(&h0);
                u.y = *reinterpret_cast<unsigned int*>(&h1);
                *reinterpret_cast<uint2*>(H + (size_t)gr * C + tx * 4) = u;
            }
        }
    }
}

// ---- gather over 64-feature fp16 rows: wave per node, 8 lanes x 16 B per
//      edge row, 4x unrolled => 32 edges / wave in flight; butterfly xor
//      {8,16,32} combines the 8 groups.
template <bool RELU, bool BIAS>
__global__ __launch_bounds__(256) void gather64h_kernel(const __half* __restrict__ Hh,
                                                        const int2* __restrict__ csr,
                                                        const int* __restrict__ rowstart,
                                                        const float* __restrict__ dinv,
                                                        const float* __restrict__ b,
                                                        __half* __restrict__ Oh, int n, int E) {
    int node = (blockIdx.x * blockDim.x + threadIdx.x) >> 6;
    if (node >= n) return;
    int lane = threadIdx.x & 63;
    int g = lane >> 3;          // 8 edge groups
    int fl = lane & 7;          // 16 B chunk (8 features) within row
    const float4* H4 = reinterpret_cast<const float4*>(Hh);
    int rs = rowstart[node];
    int re = (node + 1 < n) ? rowstart[node + 1] : E;
    float a[8] = {};
    for (int e = rs + g; e < re; e += 32) {
        int2 c[4]; float nrm[4]; float4 raw[4];
#pragma unroll
        for (int u = 0; u < 4; ++u) {
            int ee = e + u * 8;
            bool valid = ee < re;
            c[u] = csr[valid ? ee : e];
            nrm[u] = valid ? __int_as_float(c[u].y) : 0.0f;
        }
#pragma unroll
        for (int u = 0; u < 4; ++u)
            raw[u] = H4[(size_t)c[u].x * 8 + fl];
#pragma unroll
        for (int u = 0; u < 4; ++u) {
            const __half2* hp = reinterpret_cast<const __half2*>(&raw[u]);
#pragma unroll
            for (int q = 0; q < 4; ++q) {
                float2 f = __half22float2(hp[q]);
                a[2 * q]     += f.x * nrm[u];
                a[2 * q + 1] += f.y * nrm[u];
            }
        }
    }
    if (g == 0) {  // self-loop + bias counted exactly once (pre-butterfly)
        float di = dinv[node];
        float d2 = di * di;
        float4 raw = H4[(size_t)node * 8 + fl];
        const __half2* hp = reinterpret_cast<const __half2*>(&raw);
#pragma unroll
        for (int q = 0; q < 4; ++q) {
            float2 f = __half22float2(hp[q]);
            a[2 * q]     += f.x * d2;
            a[2 * q + 1] += f.y * d2;
        }
        if (BIAS) {
            float4 b0 = reinterpret_cast<const float4*>(b)[fl * 2];
            float4 b1 = reinterpret_cast<const float4*>(b)[fl * 2 + 1];
            a[0] += b0.x; a[1] += b0.y; a[2] += b0.z; a[3] += b0.w;
            a[4] += b1.x; a[5] += b1.y; a[6] += b1.z; a[7] += b1.w;
        }
    }
#pragma unroll
    for (int off = 8; off <= 32; off <<= 1) {
#pragma unroll
        for (int q = 0; q < 8; ++q) a[q] += __shfl_xor(a[q], off);
    }
    if (g == 0) {
        if (RELU) {
#pragma unroll
            for (int q = 0; q < 8; ++q) a[q] = fmaxf(a[q], 0.f);
        }
        float4 o;
        __half2* op = reinterpret_cast<__half2*>(&o);
#pragma unroll
        for (int q = 0; q < 4; ++q)
            op[q] = __float22half2_rn(make_float2(a[2 * q], a[2 * q + 1]));
        *reinterpret_cast<float4*>(Oh + (size_t)node * 64 + fl * 8) = o;
    }
}

// ---- GEMM2 + bias + log_softmax fused: out = log_softmax(X(fp16) @ W2 + b2)
__global__ __launch_bounds__(256) void gemm2_softmax_kernel(const __half* __restrict__ Xh,
                                                            const float* __restrict__ W,
                                                            const float* __restrict__ b,
                                                            float* __restrict__ out, int n) {
    constexpr int BM = 96, K = 64, C = 40, XP = 68, HP = 41;
    __shared__ float Xs[BM * XP];     // reused as Hs[96][41] after compute
    __shared__ float Ws[K * C];
    __shared__ float bs[C];
    __shared__ float rowm[BM], rowls[BM];
    int t = threadIdx.x;
    int tx = t % (C / 4);             // 0..9
    int ty = t / (C / 4);             // 0..25
    bool active = ty < BM / 4;        // ty < 24
    int rowbase = blockIdx.x * BM;

    for (int i = t; i < K * C / 4; i += 256)
        ((float4*)Ws)[i] = ((const float4*)W)[i];
    if (t < C) bs[t] = b[t];
    for (int fi = t; fi < BM * 8; fi += 256) {
        int row = fi >> 3, kq = fi & 7;
        int gr = rowbase + row; if (gr >= n) gr = n - 1;
        float4 raw = reinterpret_cast<const float4*>(Xh + (size_t)gr * K)[kq];
        const __half2* hp = reinterpret_cast<const __half2*>(&raw);
        float2 f0 = __half22float2(hp[0]), f1 = __half22float2(hp[1]);
        float2 f2 = __half22float2(hp[2]), f3 = __half22float2(hp[3]);
        float* dp = &Xs[row * XP + kq * 8];
        *reinterpret_cast<float4*>(dp)     = make_float4(f0.x, f0.y, f1.x, f1.y);
        *reinterpret_cast<float4*>(dp + 4) = make_float4(f2.x, f2.y, f3.x, f3.y);
    }
    __syncthreads();

    float acc[4][4] = {};
    if (active) {
#pragma unroll
        for (int k0 = 0; k0 < K; k0 += 4) {
            float4 xq[4], wq[4];
#pragma unroll
            for (int i = 0; i < 4; ++i)
                xq[i] = *reinterpret_cast<const float4*>(&Xs[(ty * 4 + i) * XP + k0]);
#pragma unroll
            for (int j = 0; j < 4; ++j)
                wq[j] = *reinterpret_cast<const float4*>(&Ws[(k0 + j) * C + tx * 4]);
#pragma unroll
            for (int i = 0; i < 4; ++i) {
                const float* xa = reinterpret_cast<const float*>(&xq[i]);
#pragma unroll
                for (int j = 0; j < 4; ++j) {
                    const float* wb = reinterpret_cast<const float*>(&wq[j]);
                    acc[i][0] += xa[j] * wb[0];
                    acc[i][1] += xa[j] * wb[1];
                    acc[i][2] += xa[j] * wb[2];
                    acc[i][3] += xa[j] * wb[3];
                }
            }
        }
    }
    __syncthreads();                  // everyone done reading Xs
    float* Hs = Xs;                   // reuse as [BM][41]
    if (active) {
#pragma unroll
        for (int i = 0; i < 4; ++i) {
            int r = ty * 4 + i;
#pragma unroll
            for (int j = 0; j < 4; ++j)
                Hs[r * HP + tx * 4 + j] = acc[i][j] + bs[tx * 4 + j];
        }
    }
    __syncthreads();
    if (t < BM) {
        float m = -INFINITY;
        for (int j = 0; j < C; ++j) m = fmaxf(m, Hs[t * HP + j]);
        float s = 0.f;
        for (int j = 0; j < C; ++j) s += __expf(Hs[t * HP + j] - m);
        rowm[t] = m; rowls[t] = __logf(s);
    }
    __syncthreads();
    for (int idx = t; idx < BM * C; idx += 256) {
        int r = idx / C, c = idx - r * C;
        int gr = rowbase + r;
        if (gr < n) out[(size_t)gr * C + c] = Hs[r * HP + c] - rowm[r] - rowls[r];
    }
}

extern "C" void kernel_launch(void* const* d_in, const int* in_sizes, int n_in,
                              void* d_out, int out_size, void* d_ws, size_t ws_size,
                              hipStream_t stream) {
    const float* x  = (const float*)d_in[0];
    const int*   ei = (const int*)d_in[1];
    const float* W1 = (const float*)d_in[2];
    const float* b1 = (const float*)d_in[3];
    const float* W2 = (const float*)d_in[4];
    const float* b2 = (const float*)d_in[5];
    float* out = (float*)d_out;

    const int n = in_sizes[0] / 128;   // 100000
    const int E = in_sizes[1] / 2;     // 800000
    const int* src = ei;
    const int* dst = ei + E;

    auto al = [](size_t x) { return (x + 255) & ~(size_t)255; };
    float* ws = (float*)d_ws;
    size_t o_deg  = 0;                          // n ints -> dinv floats in place
    size_t o_cnt  = al(n);                      // n ints (rowstart)
    size_t o_part = o_cnt + al(n);              // <=256 ints
    size_t o_rank = o_part + 1024;              // E ints
    size_t o_csr  = o_rank + al(E);             // E int2
    size_t o_h1   = o_csr + al((size_t)2 * E);  // n*64 halves (h1, later agg2)
    size_t o_out1 = o_h1 + al((size_t)n * 32);  // n*64 halves

    int*    degi     = (int*)(ws + o_deg);
    float*  dinv     = (float*)(ws + o_deg);
    int*    rowstart = (int*)(ws + o_cnt);
    int*    partial  = (int*)(ws + o_part);
    int*    rank     = (int*)(ws + o_rank);
    int2*   csr      = (int2*)(ws + o_csr);
    __half* h1       = (__half*)(ws + o_h1);
    __half* out1     = (__half*)(ws + o_out1);
    __half* agg2     = (__half*)(ws + o_h1);    // h1 dead after gather #1

    const int NB = (n + 1023) / 1024;

    zero_kernel<<<(n + 255) / 256, 256, 0, stream>>>(degi, n);
    deg_rank_kernel<<<(E + 255) / 256, 256, 0, stream>>>(dst, degi, rank, E);
    blocksum_kernel<<<NB, 256, 0, stream>>>(degi, partial, n);
    offsets_kernel<<<NB, 256, 0, stream>>>(degi, partial, rowstart, n, NB);
    fill_kernel<<<(E + 255) / 256, 256, 0, stream>>>(src, dst, rank, dinv, rowstart, csr, E);

    gemm_tiled_h<128, 64, 64><<<(n + 63) / 64, 256, 0, stream>>>(x, W1, h1, n);
    gather64h_kernel<true, true><<<(n + 3) / 4, 256, 0, stream>>>(
        h1, csr, rowstart, dinv, b1, out1, n, E);
    gather64h_kernel<false, false><<<(n + 3) / 4, 256, 0, stream>>>(
        out1, csr, rowstart, dinv, nullptr, agg2, n, E);
    gemm2_softmax_kernel<<<(n + 95) / 96, 256, 0, stream>>>(agg2, W2, b2, out, n);
}

// Round 8
// 187.683 us; speedup vs baseline: 1.0251x; 1.0251x over previous
//
#include <hip/hip_runtime.h>
#include <hip/hip_fp16.h>
#include <math.h>

// ---------------------------------------------------------------------------
// GCN 2-layer, CSR-gather formulation, fp16 intermediate storage + fp16 math:
//   rank[e] = atomicAdd(degi[dst[e]],1)      (histogram + rank in one pass)
//   rowstart = exscan(degi); dinv = rsqrt(degi+1)
//   csr[rowstart[t] + rank[e]] = (src, half2(nrm,nrm))    (atomic-free fill)
//   h1(fp16) = x @ W1;  out1(fp16) = relu(gather(h1) + self + b1)
//   agg2(fp16) = gather(out1) + self     (linearity: aggregate BEFORE gemm2)
//   out = log_softmax(agg2 @ W2 + b2)    (softmax fused into gemm2 epilogue)
// ---------------------------------------------------------------------------

__global__ void zero_kernel(int* __restrict__ p, int n) {
    int i = blockIdx.x * blockDim.x + threadIdx.x;
    if (i < n) p[i] = 0;
}

__global__ void deg_rank_kernel(const int* __restrict__ dst, int* __restrict__ degi,
                                int* __restrict__ rank, int E) {
    int i = blockIdx.x * blockDim.x + threadIdx.x;
    if (i < E) rank[i] = atomicAdd(&degi[dst[i]], 1);
}

// ---- block sums of degi (1024 items / block) ----
__global__ __launch_bounds__(256) void blocksum_kernel(const int* __restrict__ degi,
                                                       int* __restrict__ partial, int n) {
    __shared__ int sm[256];
    int t = threadIdx.x;
    int base = blockIdx.x * 1024 + t * 4;
    int s = 0;
#pragma unroll
    for (int j = 0; j < 4; ++j) { int i = base + j; if (i < n) s += degi[i]; }
    sm[t] = s;
    __syncthreads();
    for (int off = 128; off > 0; off >>= 1) {
        if (t < off) sm[t] += sm[t + off];
        __syncthreads();
    }
    if (t == 0) partial[blockIdx.x] = sm[0];
}

// rowstart = exscan(degi); partial-scan fused (each block scans all partials);
// also degi <- rsqrt(degi+1) in place (dinv)
__global__ __launch_bounds__(256) void offsets_kernel(int* __restrict__ degi,
                                                      const int* __restrict__ partial,
                                                      int* __restrict__ rowstart,
                                                      int n, int nb) {
    __shared__ int sm[256];
    __shared__ int pbase_s;
    int t = threadIdx.x;
    int pv = (t < nb) ? partial[t] : 0;
    sm[t] = pv;
    __syncthreads();
    for (int off = 1; off < 256; off <<= 1) {
        int x = (t >= off) ? sm[t - off] : 0;
        __syncthreads();
        sm[t] += x;
        __syncthreads();
    }
    if (t == 0) pbase_s = (blockIdx.x > 0) ? sm[blockIdx.x - 1] : 0;
    __syncthreads();
    int pbase = pbase_s;
    __syncthreads();   // sm about to be reused

    int base = blockIdx.x * 1024 + t * 4;
    int v[4]; int s = 0;
#pragma unroll
    for (int j = 0; j < 4; ++j) { v[j] = (base + j < n) ? degi[base + j] : 0; s += v[j]; }
    sm[t] = s;
    __syncthreads();
    for (int off = 1; off < 256; off <<= 1) {
        int x = (t >= off) ? sm[t - off] : 0;
        __syncthreads();
        sm[t] += x;
        __syncthreads();
    }
    int run = pbase + (sm[t] - s);
#pragma unroll
    for (int j = 0; j < 4; ++j) {
        if (base + j < n) {
            rowstart[base + j] = run; run += v[j];
            ((float*)degi)[base + j] = rsqrtf((float)v[j] + 1.0f);  // +1 self-loop
        }
    }
}

// atomic-free fill: pos = rowstart[t] + rank[e]; norm packed as half2
__global__ void fill_kernel(const int* __restrict__ src, const int* __restrict__ dst,
                            const int* __restrict__ rank, const float* __restrict__ dinv,
                            const int* __restrict__ rowstart, int2* __restrict__ csr, int E) {
    int e = blockIdx.x * blockDim.x + threadIdx.x;
    if (e >= E) return;
    int s = src[e], t = dst[e];
    float nrm = dinv[s] * dinv[t];
    unsigned short us = __half_as_ushort(__float2half_rn(nrm));
    int packed = (int)(((unsigned)us << 16) | us);
    int pos = rowstart[t] + rank[e];
    csr[pos] = make_int2(s, packed);
}

// ---- GEMM1: H[n,64](fp16) = X[n,128] @ W[128,64], 4x4 regs/thread ----
template <int K, int C, int BM>
__global__ __launch_bounds__(256) void gemm_tiled_h(const float* __restrict__ X,
                                                    const float* __restrict__ W,
                                                    __half* __restrict__ H, int n) {
    constexpr int BK = 32;
    constexpr int XP = 36;
    constexpr int ROWG = BM / 4;
    constexpr int COLG = C / 4;
    __shared__ float Xs[BM][XP];
    __shared__ float Ws[BK][C];
    int t = threadIdx.x;
    int tx = t % COLG;
    int ty = t / COLG;
    bool active = ty < ROWG;
    int rowbase = blockIdx.x * BM;
    float acc[4][4] = {};

    for (int kc = 0; kc < K; kc += BK) {
        for (int fi = t; fi < BM * 8; fi += 256) {
            int row = fi >> 3, kq = fi & 7;
            int gr = rowbase + row; if (gr >= n) gr = n - 1;
            float4 v = *reinterpret_cast<const float4*>(X + (size_t)gr * K + kc + kq * 4);
            *reinterpret_cast<float4*>(&Xs[row][kq * 4]) = v;
        }
        for (int fi = t; fi < BK * C / 4; fi += 256) {
            reinterpret_cast<float4*>(&Ws[0][0])[fi] =
                reinterpret_cast<const float4*>(W + (size_t)kc * C)[fi];
        }
        __syncthreads();
        if (active) {
#pragma unroll
            for (int k0 = 0; k0 < BK; k0 += 4) {
                float4 xq[4], wq[4];
#pragma unroll
                for (int i = 0; i < 4; ++i)
                    xq[i] = *reinterpret_cast<const float4*>(&Xs[ty * 4 + i][k0]);
#pragma unroll
                for (int j = 0; j < 4; ++j)
                    wq[j] = *reinterpret_cast<const float4*>(&Ws[k0 + j][tx * 4]);
#pragma unroll
                for (int i = 0; i < 4; ++i) {
                    const float* xa = reinterpret_cast<const float*>(&xq[i]);
#pragma unroll
                    for (int j = 0; j < 4; ++j) {
                        const float* wb = reinterpret_cast<const float*>(&wq[j]);
                        acc[i][0] += xa[j] * wb[0];
                        acc[i][1] += xa[j] * wb[1];
                        acc[i][2] += xa[j] * wb[2];
                        acc[i][3] += xa[j] * wb[3];
                    }
                }
            }
        }
        __syncthreads();
    }
    if (active) {
#pragma unroll
        for (int i = 0; i < 4; ++i) {
            int gr = rowbase + ty * 4 + i;
            if (gr < n) {
                __half2 h0 = __float22half2_rn(make_float2(acc[i][0], acc[i][1]));
                __half2 h1 = __float22half2_rn(make_float2(acc[i][2], acc[i][3]));
                uint2 u;
                u.x = *reinterpret_cast<unsigned int*>(&h0);
                u.y = *reinterpret_cast<unsigned int*>(&h1);
                *reinterpret_cast<uint2*>(H + (size_t)gr * C + tx * 4) = u;
            }
        }
    }
}

// branch-free half2 ReLU (sign-mask bit trick; avoids __hmax2 overload issues)
static __device__ __forceinline__ __half2 relu_h2(__half2 v) {
    unsigned u = *reinterpret_cast<unsigned*>(&v);
    unsigned neg = (u >> 15) & 0x00010001u;   // 1 per lane if sign bit set
    u &= ~(neg * 0xFFFFu);                    // zero negative lanes
    return *reinterpret_cast<__half2*>(&u);
}

// ---- gather over 64-feature fp16 rows: wave per node, 8 lanes x 16 B per
//      edge row, 4x unrolled => 32 edges / wave in flight; packed fp16
//      accumulate (v_pk_fma_f16); half2 butterfly xor {8,16,32}.
template <bool RELU, bool BIAS>
__global__ __launch_bounds__(256) void gather64h_kernel(const __half* __restrict__ Hh,
                                                        const int2* __restrict__ csr,
                                                        const int* __restrict__ rowstart,
                                                        const float* __restrict__ dinv,
                                                        const float* __restrict__ b,
                                                        __half* __restrict__ Oh, int n, int E) {
    int node = (blockIdx.x * blockDim.x + threadIdx.x) >> 6;
    if (node >= n) return;
    int lane = threadIdx.x & 63;
    int g = lane >> 3;          // 8 edge groups
    int fl = lane & 7;          // 16 B chunk (8 features) within row
    const float4* H4 = reinterpret_cast<const float4*>(Hh);
    int rs = rowstart[node];
    int re = (node + 1 < n) ? rowstart[node + 1] : E;
    __half2 acc[4];
#pragma unroll
    for (int q = 0; q < 4; ++q) acc[q] = __float2half2_rn(0.0f);

    for (int e = rs + g; e < re; e += 32) {
        int2 c[4]; __half2 nh[4]; float4 raw[4];
#pragma unroll
        for (int u = 0; u < 4; ++u) {
            int ee = e + u * 8;
            bool valid = ee < re;
            c[u] = csr[valid ? ee : e];
            int ni = valid ? c[u].y : 0;       // packed-zero norm for dead slots
            nh[u] = *reinterpret_cast<__half2*>(&ni);
        }
#pragma unroll
        for (int u = 0; u < 4; ++u)
            raw[u] = H4[c[u].x * 8 + fl];
#pragma unroll
        for (int u = 0; u < 4; ++u) {
            const __half2* hp = reinterpret_cast<const __half2*>(&raw[u]);
#pragma unroll
            for (int q = 0; q < 4; ++q)
                acc[q] = __hfma2(hp[q], nh[u], acc[q]);
        }
    }
    if (g == 0) {  // self-loop counted exactly once (pre-butterfly)
        float di = dinv[node];
        __half2 d2 = __float2half2_rn(di * di);
        float4 raw = H4[node * 8 + fl];
        const __half2* hp = reinterpret_cast<const __half2*>(&raw);
#pragma unroll
        for (int q = 0; q < 4; ++q) acc[q] = __hfma2(hp[q], d2, acc[q]);
    }
#pragma unroll
    for (int off = 8; off <= 32; off <<= 1) {
#pragma unroll
        for (int q = 0; q < 4; ++q) {
            int ai = *reinterpret_cast<int*>(&acc[q]);
            int bi = __shfl_xor(ai, off);
            acc[q] = __hadd2(acc[q], *reinterpret_cast<__half2*>(&bi));
        }
    }
    if (g == 0) {
        if (BIAS) {
            float4 b0 = reinterpret_cast<const float4*>(b)[fl * 2];
            float4 b1 = reinterpret_cast<const float4*>(b)[fl * 2 + 1];
            acc[0] = __hadd2(acc[0], __float22half2_rn(make_float2(b0.x, b0.y)));
            acc[1] = __hadd2(acc[1], __float22half2_rn(make_float2(b0.z, b0.w)));
            acc[2] = __hadd2(acc[2], __float22half2_rn(make_float2(b1.x, b1.y)));
            acc[3] = __hadd2(acc[3], __float22half2_rn(make_float2(b1.z, b1.w)));
        }
        if (RELU) {
#pragma unroll
            for (int q = 0; q < 4; ++q) acc[q] = relu_h2(acc[q]);
        }
        float4 o;
        __half2* op = reinterpret_cast<__half2*>(&o);
#pragma unroll
        for (int q = 0; q < 4; ++q) op[q] = acc[q];
        *reinterpret_cast<float4*>(Oh + (size_t)node * 64 + fl * 8) = o;
    }
}

// ---- GEMM2 + bias + log_softmax fused: out = log_softmax(X(fp16) @ W2 + b2)
__global__ __launch_bounds__(256) void gemm2_softmax_kernel(const __half* __restrict__ Xh,
                                                            const float* __restrict__ W,
                                                            const float* __restrict__ b,
                                                            float* __restrict__ out, int n) {
    constexpr int BM = 96, K = 64, C = 40, XP = 68, HP = 41;
    __shared__ float Xs[BM * XP];     // reused as Hs[96][41] after compute
    __shared__ float Ws[K * C];
    __shared__ float bs[C];
    __shared__ float rowm[BM], rowls[BM];
    int t = threadIdx.x;
    int tx = t % (C / 4);             // 0..9
    int ty = t / (C / 4);             // 0..25
    bool active = ty < BM / 4;        // ty < 24
    int rowbase = blockIdx.x * BM;

    for (int i = t; i < K * C / 4; i += 256)
        ((float4*)Ws)[i] = ((const float4*)W)[i];
    if (t < C) bs[t] = b[t];
    for (int fi = t; fi < BM * 8; fi += 256) {
        int row = fi >> 3, kq = fi & 7;
        int gr = rowbase + row; if (gr >= n) gr = n - 1;
        float4 raw = reinterpret_cast<const float4*>(Xh + (size_t)gr * K)[kq];
        const __half2* hp = reinterpret_cast<const __half2*>(&raw);
        float2 f0 = __half22float2(hp[0]), f1 = __half22float2(hp[1]);
        float2 f2 = __half22float2(hp[2]), f3 = __half22float2(hp[3]);
        float* dp = &Xs[row * XP + kq * 8];
        *reinterpret_cast<float4*>(dp)     = make_float4(f0.x, f0.y, f1.x, f1.y);
        *reinterpret_cast<float4*>(dp + 4) = make_float4(f2.x, f2.y, f3.x, f3.y);
    }
    __syncthreads();

    float acc[4][4] = {};
    if (active) {
#pragma unroll
        for (int k0 = 0; k0 < K; k0 += 4) {
            float4 xq[4], wq[4];
#pragma unroll
            for (int i = 0; i < 4; ++i)
                xq[i] = *reinterpret_cast<const float4*>(&Xs[(ty * 4 + i) * XP + k0]);
#pragma unroll
            for (int j = 0; j < 4; ++j)
                wq[j] = *reinterpret_cast<const float4*>(&Ws[(k0 + j) * C + tx * 4]);
#pragma unroll
            for (int i = 0; i < 4; ++i) {
                const float* xa = reinterpret_cast<const float*>(&xq[i]);
#pragma unroll
                for (int j = 0; j < 4; ++j) {
                    const float* wb = reinterpret_cast<const float*>(&wq[j]);
                    acc[i][0] += xa[j] * wb[0];
                    acc[i][1] += xa[j] * wb[1];
                    acc[i][2] += xa[j] * wb[2];
                    acc[i][3] += xa[j] * wb[3];
                }
            }
        }
    }
    __syncthreads();                  // everyone done reading Xs
    float* Hs = Xs;                   // reuse as [BM][41]
    if (active) {
#pragma unroll
        for (int i = 0; i < 4; ++i) {
            int r = ty * 4 + i;
#pragma unroll
            for (int j = 0; j < 4; ++j)
                Hs[r * HP + tx * 4 + j] = acc[i][j] + bs[tx * 4 + j];
        }
    }
    __syncthreads();
    if (t < BM) {
        float m = -INFINITY;
        for (int j = 0; j < C; ++j) m = fmaxf(m, Hs[t * HP + j]);
        float s = 0.f;
        for (int j = 0; j < C; ++j) s += __expf(Hs[t * HP + j] - m);
        rowm[t] = m; rowls[t] = __logf(s);
    }
    __syncthreads();
    for (int idx = t; idx < BM * C; idx += 256) {
        int r = idx / C, c = idx - r * C;
        int gr = rowbase + r;
        if (gr < n) out[(size_t)gr * C + c] = Hs[r * HP + c] - rowm[r] - rowls[r];
    }
}

extern "C" void kernel_launch(void* const* d_in, const int* in_sizes, int n_in,
                              void* d_out, int out_size, void* d_ws, size_t ws_size,
                              hipStream_t stream) {
    const float* x  = (const float*)d_in[0];
    const int*   ei = (const int*)d_in[1];
    const float* W1 = (const float*)d_in[2];
    const float* b1 = (const float*)d_in[3];
    const float* W2 = (const float*)d_in[4];
    const float* b2 = (const float*)d_in[5];
    float* out = (float*)d_out;

    const int n = in_sizes[0] / 128;   // 100000
    const int E = in_sizes[1] / 2;     // 800000
    const int* src = ei;
    const int* dst = ei + E;

    auto al = [](size_t x) { return (x + 255) & ~(size_t)255; };
    float* ws = (float*)d_ws;
    size_t o_deg  = 0;                          // n ints -> dinv floats in place
    size_t o_cnt  = al(n);                      // n ints (rowstart)
    size_t o_part = o_cnt + al(n);              // <=256 ints
    size_t o_rank = o_part + 1024;              // E ints
    size_t o_csr  = o_rank + al(E);             // E int2
    size_t o_h1   = o_csr + al((size_t)2 * E);  // n*64 halves (h1, later agg2)
    size_t o_out1 = o_h1 + al((size_t)n * 32);  // n*64 halves

    int*    degi     = (int*)(ws + o_deg);
    float*  dinv     = (float*)(ws + o_deg);
    int*    rowstart = (int*)(ws + o_cnt);
    int*    partial  = (int*)(ws + o_part);
    int*    rank     = (int*)(ws + o_rank);
    int2*   csr      = (int2*)(ws + o_csr);
    __half* h1       = (__half*)(ws + o_h1);
    __half* out1     = (__half*)(ws + o_out1);
    __half* agg2     = (__half*)(ws + o_h1);    // h1 dead after gather #1

    const int NB = (n + 1023) / 1024;

    zero_kernel<<<(n + 255) / 256, 256, 0, stream>>>(degi, n);
    deg_rank_kernel<<<(E + 255) / 256, 256, 0, stream>>>(dst, degi, rank, E);
    blocksum_kernel<<<NB, 256, 0, stream>>>(degi, partial, n);
    offsets_kernel<<<NB, 256, 0, stream>>>(degi, partial, rowstart, n, NB);
    fill_kernel<<<(E + 255) / 256, 256, 0, stream>>>(src, dst, rank, dinv, rowstart, csr, E);

    gemm_tiled_h<128, 64, 64><<<(n + 63) / 64, 256, 0, stream>>>(x, W1, h1, n);
    gather64h_kernel<true, true><<<(n + 3) / 4, 256, 0, stream>>>(
        h1, csr, rowstart, dinv, b1, out1, n, E);
    gather64h_kernel<false, false><<<(n + 3) / 4, 256, 0, stream>>>(
        out1, csr, rowstart, dinv, nullptr, agg2, n, E);
    gemm2_softmax_kernel<<<(n + 95) / 96, 256, 0, stream>>>(agg2, W2, b2, out, n);
}

// Round 9
// 155.270 us; speedup vs baseline: 1.2391x; 1.2088x over previous
//
#include <hip/hip_runtime.h>
#include <hip/hip_fp16.h>
#include <math.h>

// ---------------------------------------------------------------------------
// GCN 2-layer, CSR-gather formulation, fp16 intermediate storage + fp16 math:
//   rank[e] = atomicAdd(degi[dst[e]],1)      (histogram + rank in one pass)
//   rowstart = exscan(degi); dinv = rsqrt(degi+1)
//   csr[rowstart[t] + rank[e]] = (src, half2(nrm,nrm))    (atomic-free fill)
//   h1(fp16) = x @ W1;  out1(fp16) = relu(gather(h1) + self + b1)
//   agg2(fp16) = gather(out1) + self     (linearity: aggregate BEFORE gemm2)
//   out = log_softmax(agg2 @ W2 + b2)    (softmax fused into gemm2 epilogue)
// Gather shape: 8 lanes/node (one 128B row), 8 nodes/wave, no reduction.
// ---------------------------------------------------------------------------

__global__ void zero_kernel(int* __restrict__ p, int n) {
    int i = blockIdx.x * blockDim.x + threadIdx.x;
    if (i < n) p[i] = 0;
}

__global__ void deg_rank_kernel(const int* __restrict__ dst, int* __restrict__ degi,
                                int* __restrict__ rank, int E) {
    int i = blockIdx.x * blockDim.x + threadIdx.x;
    if (i < E) rank[i] = atomicAdd(&degi[dst[i]], 1);
}

// ---- block sums of degi (1024 items / block) ----
__global__ __launch_bounds__(256) void blocksum_kernel(const int* __restrict__ degi,
                                                       int* __restrict__ partial, int n) {
    __shared__ int sm[256];
    int t = threadIdx.x;
    int base = blockIdx.x * 1024 + t * 4;
    int s = 0;
#pragma unroll
    for (int j = 0; j < 4; ++j) { int i = base + j; if (i < n) s += degi[i]; }
    sm[t] = s;
    __syncthreads();
    for (int off = 128; off > 0; off >>= 1) {
        if (t < off) sm[t] += sm[t + off];
        __syncthreads();
    }
    if (t == 0) partial[blockIdx.x] = sm[0];
}

// rowstart = exscan(degi); partial-scan fused (each block scans all partials);
// also degi <- rsqrt(degi+1) in place (dinv)
__global__ __launch_bounds__(256) void offsets_kernel(int* __restrict__ degi,
                                                      const int* __restrict__ partial,
                                                      int* __restrict__ rowstart,
                                                      int n, int nb) {
    __shared__ int sm[256];
    __shared__ int pbase_s;
    int t = threadIdx.x;
    int pv = (t < nb) ? partial[t] : 0;
    sm[t] = pv;
    __syncthreads();
    for (int off = 1; off < 256; off <<= 1) {
        int x = (t >= off) ? sm[t - off] : 0;
        __syncthreads();
        sm[t] += x;
        __syncthreads();
    }
    if (t == 0) pbase_s = (blockIdx.x > 0) ? sm[blockIdx.x - 1] : 0;
    __syncthreads();
    int pbase = pbase_s;
    __syncthreads();   // sm about to be reused

    int base = blockIdx.x * 1024 + t * 4;
    int v[4]; int s = 0;
#pragma unroll
    for (int j = 0; j < 4; ++j) { v[j] = (base + j < n) ? degi[base + j] : 0; s += v[j]; }
    sm[t] = s;
    __syncthreads();
    for (int off = 1; off < 256; off <<= 1) {
        int x = (t >= off) ? sm[t - off] : 0;
        __syncthreads();
        sm[t] += x;
        __syncthreads();
    }
    int run = pbase + (sm[t] - s);
#pragma unroll
    for (int j = 0; j < 4; ++j) {
        if (base + j < n) {
            rowstart[base + j] = run; run += v[j];
            ((float*)degi)[base + j] = rsqrtf((float)v[j] + 1.0f);  // +1 self-loop
        }
    }
}

// atomic-free fill: pos = rowstart[t] + rank[e]; norm packed as half2
__global__ void fill_kernel(const int* __restrict__ src, const int* __restrict__ dst,
                            const int* __restrict__ rank, const float* __restrict__ dinv,
                            const int* __restrict__ rowstart, int2* __restrict__ csr, int E) {
    int e = blockIdx.x * blockDim.x + threadIdx.x;
    if (e >= E) return;
    int s = src[e], t = dst[e];
    float nrm = dinv[s] * dinv[t];
    unsigned short us = __half_as_ushort(__float2half_rn(nrm));
    int packed = (int)(((unsigned)us << 16) | us);
    int pos = rowstart[t] + rank[e];
    csr[pos] = make_int2(s, packed);
}

// ---- GEMM1: H[n,64](fp16) = X[n,128] @ W[128,64], 4x4 regs/thread ----
template <int K, int C, int BM>
__global__ __launch_bounds__(256) void gemm_tiled_h(const float* __restrict__ X,
                                                    const float* __restrict__ W,
                                                    __half* __restrict__ H, int n) {
    constexpr int BK = 32;
    constexpr int XP = 36;
    constexpr int ROWG = BM / 4;
    constexpr int COLG = C / 4;
    __shared__ float Xs[BM][XP];
    __shared__ float Ws[BK][C];
    int t = threadIdx.x;
    int tx = t % COLG;
    int ty = t / COLG;
    bool active = ty < ROWG;
    int rowbase = blockIdx.x * BM;
    float acc[4][4] = {};

    for (int kc = 0; kc < K; kc += BK) {
        for (int fi = t; fi < BM * 8; fi += 256) {
            int row = fi >> 3, kq = fi & 7;
            int gr = rowbase + row; if (gr >= n) gr = n - 1;
            float4 v = *reinterpret_cast<const float4*>(X + (size_t)gr * K + kc + kq * 4);
            *reinterpret_cast<float4*>(&Xs[row][kq * 4]) = v;
        }
        for (int fi = t; fi < BK * C / 4; fi += 256) {
            reinterpret_cast<float4*>(&Ws[0][0])[fi] =
                reinterpret_cast<const float4*>(W + (size_t)kc * C)[fi];
        }
        __syncthreads();
        if (active) {
#pragma unroll
            for (int k0 = 0; k0 < BK; k0 += 4) {
                float4 xq[4], wq[4];
#pragma unroll
                for (int i = 0; i < 4; ++i)
                    xq[i] = *reinterpret_cast<const float4*>(&Xs[ty * 4 + i][k0]);
#pragma unroll
                for (int j = 0; j < 4; ++j)
                    wq[j] = *reinterpret_cast<const float4*>(&Ws[k0 + j][tx * 4]);
#pragma unroll
                for (int i = 0; i < 4; ++i) {
                    const float* xa = reinterpret_cast<const float*>(&xq[i]);
#pragma unroll
                    for (int j = 0; j < 4; ++j) {
                        const float* wb = reinterpret_cast<const float*>(&wq[j]);
                        acc[i][0] += xa[j] * wb[0];
                        acc[i][1] += xa[j] * wb[1];
                        acc[i][2] += xa[j] * wb[2];
                        acc[i][3] += xa[j] * wb[3];
                    }
                }
            }
        }
        __syncthreads();
    }
    if (active) {
#pragma unroll
        for (int i = 0; i < 4; ++i) {
            int gr = rowbase + ty * 4 + i;
            if (gr < n) {
                __half2 h0 = __float22half2_rn(make_float2(acc[i][0], acc[i][1]));
                __half2 h1 = __float22half2_rn(make_float2(acc[i][2], acc[i][3]));
                uint2 u;
                u.x = *reinterpret_cast<unsigned int*>(&h0);
                u.y = *reinterpret_cast<unsigned int*>(&h1);
                *reinterpret_cast<uint2*>(H + (size_t)gr * C + tx * 4) = u;
            }
        }
    }
}

// branch-free half2 ReLU (sign-mask bit trick; avoids __hmax2 overload issues)
static __device__ __forceinline__ __half2 relu_h2(__half2 v) {
    unsigned u = *reinterpret_cast<unsigned*>(&v);
    unsigned neg = (u >> 15) & 0x00010001u;   // 1 per lane if sign bit set
    u &= ~(neg * 0xFFFFu);                    // zero negative lanes
    return *reinterpret_cast<__half2*>(&u);
}

// ---- gather over 64-feature fp16 rows: 8 lanes per node (one 128B row),
//      8 nodes per wave, 4 edges/node in flight, NO cross-lane reduction.
//      Dead slots clamp to row 0 (L1-hit) with packed-zero norm.
template <bool RELU, bool BIAS>
__global__ __launch_bounds__(256) void gather64h_kernel(const __half* __restrict__ Hh,
                                                        const int2* __restrict__ csr,
                                                        const int* __restrict__ rowstart,
                                                        const float* __restrict__ dinv,
                                                        const float* __restrict__ b,
                                                        __half* __restrict__ Oh, int n, int E) {
    int gt = blockIdx.x * blockDim.x + threadIdx.x;
    int node = gt >> 3;
    if (node >= n) return;
    int fl = gt & 7;            // 16 B chunk (8 features) within the row
    const float4* H4 = reinterpret_cast<const float4*>(Hh);
    int rs = rowstart[node];
    int re = (node + 1 < n) ? rowstart[node + 1] : E;
    __half2 acc[4];
#pragma unroll
    for (int q = 0; q < 4; ++q) acc[q] = __float2half2_rn(0.0f);

    int e = rs;
    while (__any(e < re)) {
        int srcrow[4]; __half2 nh[4]; float4 raw[4];
#pragma unroll
        for (int u = 0; u < 4; ++u) {
            int ee = e + u;
            bool valid = ee < re;
            int2 c = csr[valid ? ee : rs];
            srcrow[u] = valid ? c.x : 0;       // dead slot -> row 0 (L1-hit)
            int ni = valid ? c.y : 0;          // packed-zero norm for dead slots
            nh[u] = *reinterpret_cast<__half2*>(&ni);
        }
#pragma unroll
        for (int u = 0; u < 4; ++u)
            raw[u] = H4[srcrow[u] * 8 + fl];
#pragma unroll
        for (int u = 0; u < 4; ++u) {
            const __half2* hp = reinterpret_cast<const __half2*>(&raw[u]);
#pragma unroll
            for (int q = 0; q < 4; ++q)
                acc[q] = __hfma2(hp[q], nh[u], acc[q]);
        }
        e += 4;
    }
    // self-loop (each lane owns its 16B chunk exactly once)
    {
        float di = dinv[node];
        __half2 d2 = __float2half2_rn(di * di);
        float4 raw = H4[node * 8 + fl];
        const __half2* hp = reinterpret_cast<const __half2*>(&raw);
#pragma unroll
        for (int q = 0; q < 4; ++q) acc[q] = __hfma2(hp[q], d2, acc[q]);
    }
    if (BIAS) {
        float4 b0 = reinterpret_cast<const float4*>(b)[fl * 2];
        float4 b1 = reinterpret_cast<const float4*>(b)[fl * 2 + 1];
        acc[0] = __hadd2(acc[0], __float22half2_rn(make_float2(b0.x, b0.y)));
        acc[1] = __hadd2(acc[1], __float22half2_rn(make_float2(b0.z, b0.w)));
        acc[2] = __hadd2(acc[2], __float22half2_rn(make_float2(b1.x, b1.y)));
        acc[3] = __hadd2(acc[3], __float22half2_rn(make_float2(b1.z, b1.w)));
    }
    if (RELU) {
#pragma unroll
        for (int q = 0; q < 4; ++q) acc[q] = relu_h2(acc[q]);
    }
    float4 o;
    __half2* op = reinterpret_cast<__half2*>(&o);
#pragma unroll
    for (int q = 0; q < 4; ++q) op[q] = acc[q];
    *reinterpret_cast<float4*>(Oh + (size_t)node * 64 + fl * 8) = o;
}

// ---- GEMM2 + bias + log_softmax fused: out = log_softmax(X(fp16) @ W2 + b2)
__global__ __launch_bounds__(256) void gemm2_softmax_kernel(const __half* __restrict__ Xh,
                                                            const float* __restrict__ W,
                                                            const float* __restrict__ b,
                                                            float* __restrict__ out, int n) {
    constexpr int BM = 96, K = 64, C = 40, XP = 68, HP = 41;
    __shared__ float Xs[BM * XP];     // reused as Hs[96][41] after compute
    __shared__ float Ws[K * C];
    __shared__ float bs[C];
    __shared__ float rowm[BM], rowls[BM];
    int t = threadIdx.x;
    int tx = t % (C / 4);             // 0..9
    int ty = t / (C / 4);             // 0..25
    bool active = ty < BM / 4;        // ty < 24
    int rowbase = blockIdx.x * BM;

    for (int i = t; i < K * C / 4; i += 256)
        ((float4*)Ws)[i] = ((const float4*)W)[i];
    if (t < C) bs[t] = b[t];
    for (int fi = t; fi < BM * 8; fi += 256) {
        int row = fi >> 3, kq = fi & 7;
        int gr = rowbase + row; if (gr >= n) gr = n - 1;
        float4 raw = reinterpret_cast<const float4*>(Xh + (size_t)gr * K)[kq];
        const __half2* hp = reinterpret_cast<const __half2*>(&raw);
        float2 f0 = __half22float2(hp[0]), f1 = __half22float2(hp[1]);
        float2 f2 = __half22float2(hp[2]), f3 = __half22float2(hp[3]);
        float* dp = &Xs[row * XP + kq * 8];
        *reinterpret_cast<float4*>(dp)     = make_float4(f0.x, f0.y, f1.x, f1.y);
        *reinterpret_cast<float4*>(dp + 4) = make_float4(f2.x, f2.y, f3.x, f3.y);
    }
    __syncthreads();

    float acc[4][4] = {};
    if (active) {
#pragma unroll
        for (int k0 = 0; k0 < K; k0 += 4) {
            float4 xq[4], wq[4];
#pragma unroll
            for (int i = 0; i < 4; ++i)
                xq[i] = *reinterpret_cast<const float4*>(&Xs[(ty * 4 + i) * XP + k0]);
#pragma unroll
            for (int j = 0; j < 4; ++j)
                wq[j] = *reinterpret_cast<const float4*>(&Ws[(k0 + j) * C + tx * 4]);
#pragma unroll
            for (int i = 0; i < 4; ++i) {
                const float* xa = reinterpret_cast<const float*>(&xq[i]);
#pragma unroll
                for (int j = 0; j < 4; ++j) {
                    const float* wb = reinterpret_cast<const float*>(&wq[j]);
                    acc[i][0] += xa[j] * wb[0];
                    acc[i][1] += xa[j] * wb[1];
                    acc[i][2] += xa[j] * wb[2];
                    acc[i][3] += xa[j] * wb[3];
                }
            }
        }
    }
    __syncthreads();                  // everyone done reading Xs
    float* Hs = Xs;                   // reuse as [BM][41]
    if (active) {
#pragma unroll
        for (int i = 0; i < 4; ++i) {
            int r = ty * 4 + i;
#pragma unroll
            for (int j = 0; j < 4; ++j)
                Hs[r * HP + tx * 4 + j] = acc[i][j] + bs[tx * 4 + j];
        }
    }
    __syncthreads();
    if (t < BM) {
        float m = -INFINITY;
        for (int j = 0; j < C; ++j) m = fmaxf(m, Hs[t * HP + j]);
        float s = 0.f;
        for (int j = 0; j < C; ++j) s += __expf(Hs[t * HP + j] - m);
        rowm[t] = m; rowls[t] = __logf(s);
    }
    __syncthreads();
    for (int idx = t; idx < BM * C; idx += 256) {
        int r = idx / C, c = idx - r * C;
        int gr = rowbase + r;
        if (gr < n) out[(size_t)gr * C + c] = Hs[r * HP + c] - rowm[r] - rowls[r];
    }
}

extern "C" void kernel_launch(void* const* d_in, const int* in_sizes, int n_in,
                              void* d_out, int out_size, void* d_ws, size_t ws_size,
                              hipStream_t stream) {
    const float* x  = (const float*)d_in[0];
    const int*   ei = (const int*)d_in[1];
    const float* W1 = (const float*)d_in[2];
    const float* b1 = (const float*)d_in[3];
    const float* W2 = (const float*)d_in[4];
    const float* b2 = (const float*)d_in[5];
    float* out = (float*)d_out;

    const int n = in_sizes[0] / 128;   // 100000
    const int E = in_sizes[1] / 2;     // 800000
    const int* src = ei;
    const int* dst = ei + E;

    auto al = [](size_t x) { return (x + 255) & ~(size_t)255; };
    float* ws = (float*)d_ws;
    size_t o_deg  = 0;                          // n ints -> dinv floats in place
    size_t o_cnt  = al(n);                      // n ints (rowstart)
    size_t o_part = o_cnt + al(n);              // <=256 ints
    size_t o_rank = o_part + 1024;              // E ints
    size_t o_csr  = o_rank + al(E);             // E int2
    size_t o_h1   = o_csr + al((size_t)2 * E);  // n*64 halves (h1, later agg2)
    size_t o_out1 = o_h1 + al((size_t)n * 32);  // n*64 halves

    int*    degi     = (int*)(ws + o_deg);
    float*  dinv     = (float*)(ws + o_deg);
    int*    rowstart = (int*)(ws + o_cnt);
    int*    partial  = (int*)(ws + o_part);
    int*    rank     = (int*)(ws + o_rank);
    int2*   csr      = (int2*)(ws + o_csr);
    __half* h1       = (__half*)(ws + o_h1);
    __half* out1     = (__half*)(ws + o_out1);
    __half* agg2     = (__half*)(ws + o_h1);    // h1 dead after gather #1

    const int NB = (n + 1023) / 1024;

    zero_kernel<<<(n + 255) / 256, 256, 0, stream>>>(degi, n);
    deg_rank_kernel<<<(E + 255) / 256, 256, 0, stream>>>(dst, degi, rank, E);
    blocksum_kernel<<<NB, 256, 0, stream>>>(degi, partial, n);
    offsets_kernel<<<NB, 256, 0, stream>>>(degi, partial, rowstart, n, NB);
    fill_kernel<<<(E + 255) / 256, 256, 0, stream>>>(src, dst, rank, dinv, rowstart, csr, E);

    gemm_tiled_h<128, 64, 64><<<(n + 63) / 64, 256, 0, stream>>>(x, W1, h1, n);
    gather64h_kernel<true, true><<<((size_t)n * 8 + 255) / 256, 256, 0, stream>>>(
        h1, csr, rowstart, dinv, b1, out1, n, E);
    gather64h_kernel<false, false><<<((size_t)n * 8 + 255) / 256, 256, 0, stream>>>(
        out1, csr, rowstart, dinv, nullptr, agg2, n, E);
    gemm2_softmax_kernel<<<(n + 95) / 96, 256, 0, stream>>>(agg2, W2, b2, out, n);
}

// Round 10
// 144.182 us; speedup vs baseline: 1.3344x; 1.0769x over previous
//
#include <hip/hip_runtime.h>
#include <hip/hip_fp16.h>
#include <math.h>

// ---------------------------------------------------------------------------
// GCN 2-layer, CSR-gather formulation, fp16 intermediate storage + fp16 math:
//   rank[e] = atomicAdd(degi[dst[e]],1)      (histogram + rank in one pass)
//   rowstart = exscan(degi); dinv = rsqrt(degi+1)
//   csr[rowstart[t] + rank[e]] = (src, half2(nrm,nrm))    (atomic-free fill)
//   h1(fp16) = x @ W1   -- MFMA 16x16x32_f16, fp32 accumulate
//   out1(fp16) = relu(gather(h1) + self + b1)
//   agg2(fp16) = gather(out1) + self     (linearity: aggregate BEFORE gemm2)
//   out = log_softmax(agg2 @ W2 + b2)    (softmax fused into gemm2 epilogue)
// Gather shape: 8 lanes/node (one 128B row), 8 nodes/wave, no reduction.
// ---------------------------------------------------------------------------

typedef _Float16 f16x4 __attribute__((ext_vector_type(4)));
typedef _Float16 f16x8 __attribute__((ext_vector_type(8)));
typedef float    f32x4 __attribute__((ext_vector_type(4)));

__global__ void zero_kernel(int* __restrict__ p, int n) {
    int i = blockIdx.x * blockDim.x + threadIdx.x;
    if (i < n) p[i] = 0;
}

__global__ void deg_rank_kernel(const int* __restrict__ dst, int* __restrict__ degi,
                                int* __restrict__ rank, int E) {
    int i = blockIdx.x * blockDim.x + threadIdx.x;
    if (i < E) rank[i] = atomicAdd(&degi[dst[i]], 1);
}

// ---- block sums of degi (1024 items / block) ----
__global__ __launch_bounds__(256) void blocksum_kernel(const int* __restrict__ degi,
                                                       int* __restrict__ partial, int n) {
    __shared__ int sm[256];
    int t = threadIdx.x;
    int base = blockIdx.x * 1024 + t * 4;
    int s = 0;
#pragma unroll
    for (int j = 0; j < 4; ++j) { int i = base + j; if (i < n) s += degi[i]; }
    sm[t] = s;
    __syncthreads();
    for (int off = 128; off > 0; off >>= 1) {
        if (t < off) sm[t] += sm[t + off];
        __syncthreads();
    }
    if (t == 0) partial[blockIdx.x] = sm[0];
}

// rowstart = exscan(degi); partial-scan fused (each block scans all partials);
// also degi <- rsqrt(degi+1) in place (dinv)
__global__ __launch_bounds__(256) void offsets_kernel(int* __restrict__ degi,
                                                      const int* __restrict__ partial,
                                                      int* __restrict__ rowstart,
                                                      int n, int nb) {
    __shared__ int sm[256];
    __shared__ int pbase_s;
    int t = threadIdx.x;
    int pv = (t < nb) ? partial[t] : 0;
    sm[t] = pv;
    __syncthreads();
    for (int off = 1; off < 256; off <<= 1) {
        int x = (t >= off) ? sm[t - off] : 0;
        __syncthreads();
        sm[t] += x;
        __syncthreads();
    }
    if (t == 0) pbase_s = (blockIdx.x > 0) ? sm[blockIdx.x - 1] : 0;
    __syncthreads();
    int pbase = pbase_s;
    __syncthreads();   // sm about to be reused

    int base = blockIdx.x * 1024 + t * 4;
    int v[4]; int s = 0;
#pragma unroll
    for (int j = 0; j < 4; ++j) { v[j] = (base + j < n) ? degi[base + j] : 0; s += v[j]; }
    sm[t] = s;
    __syncthreads();
    for (int off = 1; off < 256; off <<= 1) {
        int x = (t >= off) ? sm[t - off] : 0;
        __syncthreads();
        sm[t] += x;
        __syncthreads();
    }
    int run = pbase + (sm[t] - s);
#pragma unroll
    for (int j = 0; j < 4; ++j) {
        if (base + j < n) {
            rowstart[base + j] = run; run += v[j];
            ((float*)degi)[base + j] = rsqrtf((float)v[j] + 1.0f);  // +1 self-loop
        }
    }
}

// atomic-free fill: pos = rowstart[t] + rank[e]; norm packed as half2
__global__ void fill_kernel(const int* __restrict__ src, const int* __restrict__ dst,
                            const int* __restrict__ rank, const float* __restrict__ dinv,
                            const int* __restrict__ rowstart, int2* __restrict__ csr, int E) {
    int e = blockIdx.x * blockDim.x + threadIdx.x;
    if (e >= E) return;
    int s = src[e], t = dst[e];
    float nrm = dinv[s] * dinv[t];
    unsigned short us = __half_as_ushort(__float2half_rn(nrm));
    int packed = (int)(((unsigned)us << 16) | us);
    int pos = rowstart[t] + rank[e];
    csr[pos] = make_int2(s, packed);
}

// ---- GEMM1 via MFMA: H[n,64](fp16) = X[n,128](fp32->fp16) @ W[128,64] ----
// Block: 64 rows, 256 threads (4 waves). One-shot LDS staging, XOR-swizzled.
// Wave w owns rows 16w..16w+15; 4 n-tiles of 16 cols; K=128 as 4 MFMA chunks.
__global__ __launch_bounds__(256) void gemm1_mfma(const float* __restrict__ X,
                                                  const float* __restrict__ W,
                                                  _Float16* __restrict__ H, int n) {
    __shared__ _Float16 Xs[64 * 128];   // [row][k], swizzled: idx ^= (row&7)<<3
    __shared__ _Float16 Ws[64 * 128];   // [nn][k] (W transposed), same swizzle
    int t = threadIdx.x;
    int rowbase = blockIdx.x * 64;

    // stage X tile: 2048 float4 reads (coalesced), convert to fp16
    for (int i = t; i < 2048; i += 256) {
        int row = i >> 5;                 // 32 float4 per 128-float row
        int k = (i & 31) * 4;
        int gr = rowbase + row; if (gr >= n) gr = n - 1;
        float4 v = *reinterpret_cast<const float4*>(X + (size_t)gr * 128 + k);
        f16x4 hv = { (_Float16)v.x, (_Float16)v.y, (_Float16)v.z, (_Float16)v.w };
        int idx = row * 128 + (k ^ ((row & 7) << 3));
        *reinterpret_cast<f16x4*>(&Xs[idx]) = hv;
    }
    // stage W transposed: W[k][nn] (row-major 128x64) -> Ws[nn][k]
    for (int i = t; i < 2048; i += 256) {
        int k = i >> 4;                   // 16 float4 per 64-float W row
        int nn0 = (i & 15) * 4;
        float4 v = *reinterpret_cast<const float4*>(W + (size_t)k * 64 + nn0);
        const float* vp = reinterpret_cast<const float*>(&v);
#pragma unroll
        for (int j = 0; j < 4; ++j) {
            int nn = nn0 + j;
            Ws[nn * 128 + (k ^ ((nn & 7) << 3))] = (_Float16)vp[j];
        }
    }
    __syncthreads();

    int w = t >> 6;             // wave 0..3
    int l = t & 63;
    int lr = l & 15;            // row-within-tile for A / col for B,D
    int lk = l >> 4;            // k-subchunk 0..3
    int arow = 16 * w + lr;

    f16x8 a[4];
#pragma unroll
    for (int kc = 0; kc < 4; ++kc) {
        int k8 = kc * 32 + lk * 8;
        a[kc] = *reinterpret_cast<f16x8*>(&Xs[arow * 128 + (k8 ^ ((arow & 7) << 3))]);
    }
    f32x4 acc[4] = {};
#pragma unroll
    for (int nt = 0; nt < 4; ++nt) {
        int nrow = 16 * nt + lr;
#pragma unroll
        for (int kc = 0; kc < 4; ++kc) {
            int k8 = kc * 32 + lk * 8;
            f16x8 b = *reinterpret_cast<f16x8*>(&Ws[nrow * 128 + (k8 ^ ((nrow & 7) << 3))]);
            acc[nt] = __builtin_amdgcn_mfma_f32_16x16x32_f16(a[kc], b, acc[nt], 0, 0, 0);
        }
    }
    // D: col = lane&15, row = (lane>>4)*4 + reg  [m89-verified]
#pragma unroll
    for (int nt = 0; nt < 4; ++nt) {
#pragma unroll
        for (int r = 0; r < 4; ++r) {
            int grow = rowbase + 16 * w + lk * 4 + r;
            if (grow < n) H[(size_t)grow * 64 + nt * 16 + lr] = (_Float16)acc[nt][r];
        }
    }
}

// branch-free half2 ReLU (sign-mask bit trick; avoids __hmax2 overload issues)
static __device__ __forceinline__ __half2 relu_h2(__half2 v) {
    unsigned u = *reinterpret_cast<unsigned*>(&v);
    unsigned neg = (u >> 15) & 0x00010001u;   // 1 per lane if sign bit set
    u &= ~(neg * 0xFFFFu);                    // zero negative lanes
    return *reinterpret_cast<__half2*>(&u);
}

// ---- gather over 64-feature fp16 rows: 8 lanes per node (one 128B row),
//      8 nodes per wave, 4 edges/node in flight, NO cross-lane reduction.
//      Dead slots clamp to row 0 (L1-hit) with packed-zero norm.
template <bool RELU, bool BIAS>
__global__ __launch_bounds__(256) void gather64h_kernel(const __half* __restrict__ Hh,
                                                        const int2* __restrict__ csr,
                                                        const int* __restrict__ rowstart,
                                                        const float* __restrict__ dinv,
                                                        const float* __restrict__ b,
                                                        __half* __restrict__ Oh, int n, int E) {
    int gt = blockIdx.x * blockDim.x + threadIdx.x;
    int node = gt >> 3;
    if (node >= n) return;
    int fl = gt & 7;            // 16 B chunk (8 features) within the row
    const float4* H4 = reinterpret_cast<const float4*>(Hh);
    int rs = rowstart[node];
    int re = (node + 1 < n) ? rowstart[node + 1] : E;
    __half2 acc[4];
#pragma unroll
    for (int q = 0; q < 4; ++q) acc[q] = __float2half2_rn(0.0f);

    int e = rs;
    while (__any(e < re)) {
        int srcrow[4]; __half2 nh[4]; float4 raw[4];
#pragma unroll
        for (int u = 0; u < 4; ++u) {
            int ee = e + u;
            bool valid = ee < re;
            int2 c = csr[valid ? ee : rs];
            srcrow[u] = valid ? c.x : 0;       // dead slot -> row 0 (L1-hit)
            int ni = valid ? c.y : 0;          // packed-zero norm for dead slots
            nh[u] = *reinterpret_cast<__half2*>(&ni);
        }
#pragma unroll
        for (int u = 0; u < 4; ++u)
            raw[u] = H4[srcrow[u] * 8 + fl];
#pragma unroll
        for (int u = 0; u < 4; ++u) {
            const __half2* hp = reinterpret_cast<const __half2*>(&raw[u]);
#pragma unroll
            for (int q = 0; q < 4; ++q)
                acc[q] = __hfma2(hp[q], nh[u], acc[q]);
        }
        e += 4;
    }
    // self-loop (each lane owns its 16B chunk exactly once)
    {
        float di = dinv[node];
        __half2 d2 = __float2half2_rn(di * di);
        float4 raw = H4[node * 8 + fl];
        const __half2* hp = reinterpret_cast<const __half2*>(&raw);
#pragma unroll
        for (int q = 0; q < 4; ++q) acc[q] = __hfma2(hp[q], d2, acc[q]);
    }
    if (BIAS) {
        float4 b0 = reinterpret_cast<const float4*>(b)[fl * 2];
        float4 b1 = reinterpret_cast<const float4*>(b)[fl * 2 + 1];
        acc[0] = __hadd2(acc[0], __float22half2_rn(make_float2(b0.x, b0.y)));
        acc[1] = __hadd2(acc[1], __float22half2_rn(make_float2(b0.z, b0.w)));
        acc[2] = __hadd2(acc[2], __float22half2_rn(make_float2(b1.x, b1.y)));
        acc[3] = __hadd2(acc[3], __float22half2_rn(make_float2(b1.z, b1.w)));
    }
    if (RELU) {
#pragma unroll
        for (int q = 0; q < 4; ++q) acc[q] = relu_h2(acc[q]);
    }
    float4 o;
    __half2* op = reinterpret_cast<__half2*>(&o);
#pragma unroll
    for (int q = 0; q < 4; ++q) op[q] = acc[q];
    *reinterpret_cast<float4*>(Oh + (size_t)node * 64 + fl * 8) = o;
}

// ---- GEMM2 + bias + log_softmax fused: out = log_softmax(X(fp16) @ W2 + b2)
__global__ __launch_bounds__(256) void gemm2_softmax_kernel(const __half* __restrict__ Xh,
                                                            const float* __restrict__ W,
                                                            const float* __restrict__ b,
                                                            float* __restrict__ out, int n) {
    constexpr int BM = 96, K = 64, C = 40, XP = 68, HP = 41;
    __shared__ float Xs[BM * XP];     // reused as Hs[96][41] after compute
    __shared__ float Ws[K * C];
    __shared__ float bs[C];
    __shared__ float rowm[BM], rowls[BM];
    int t = threadIdx.x;
    int tx = t % (C / 4);             // 0..9
    int ty = t / (C / 4);             // 0..25
    bool active = ty < BM / 4;        // ty < 24
    int rowbase = blockIdx.x * BM;

    for (int i = t; i < K * C / 4; i += 256)
        ((float4*)Ws)[i] = ((const float4*)W)[i];
    if (t < C) bs[t] = b[t];
    for (int fi = t; fi < BM * 8; fi += 256) {
        int row = fi >> 3, kq = fi & 7;
        int gr = rowbase + row; if (gr >= n) gr = n - 1;
        float4 raw = reinterpret_cast<const float4*>(Xh + (size_t)gr * K)[kq];
        const __half2* hp = reinterpret_cast<const __half2*>(&raw);
        float2 f0 = __half22float2(hp[0]), f1 = __half22float2(hp[1]);
        float2 f2 = __half22float2(hp[2]), f3 = __half22float2(hp[3]);
        float* dp = &Xs[row * XP + kq * 8];
        *reinterpret_cast<float4*>(dp)     = make_float4(f0.x, f0.y, f1.x, f1.y);
        *reinterpret_cast<float4*>(dp + 4) = make_float4(f2.x, f2.y, f3.x, f3.y);
    }
    __syncthreads();

    float acc[4][4] = {};
    if (active) {
#pragma unroll
        for (int k0 = 0; k0 < K; k0 += 4) {
            float4 xq[4], wq[4];
#pragma unroll
            for (int i = 0; i < 4; ++i)
                xq[i] = *reinterpret_cast<const float4*>(&Xs[(ty * 4 + i) * XP + k0]);
#pragma unroll
            for (int j = 0; j < 4; ++j)
                wq[j] = *reinterpret_cast<const float4*>(&Ws[(k0 + j) * C + tx * 4]);
#pragma unroll
            for (int i = 0; i < 4; ++i) {
                const float* xa = reinterpret_cast<const float*>(&xq[i]);
#pragma unroll
                for (int j = 0; j < 4; ++j) {
                    const float* wb = reinterpret_cast<const float*>(&wq[j]);
                    acc[i][0] += xa[j] * wb[0];
                    acc[i][1] += xa[j] * wb[1];
                    acc[i][2] += xa[j] * wb[2];
                    acc[i][3] += xa[j] * wb[3];
                }
            }
        }
    }
    __syncthreads();                  // everyone done reading Xs
    float* Hs = Xs;                   // reuse as [BM][41]
    if (active) {
#pragma unroll
        for (int i = 0; i < 4; ++i) {
            int r = ty * 4 + i;
#pragma unroll
            for (int j = 0; j < 4; ++j)
                Hs[r * HP + tx * 4 + j] = acc[i][j] + bs[tx * 4 + j];
        }
    }
    __syncthreads();
    if (t < BM) {
        float m = -INFINITY;
        for (int j = 0; j < C; ++j) m = fmaxf(m, Hs[t * HP + j]);
        float s = 0.f;
        for (int j = 0; j < C; ++j) s += __expf(Hs[t * HP + j] - m);
        rowm[t] = m; rowls[t] = __logf(s);
    }
    __syncthreads();
    for (int idx = t; idx < BM * C; idx += 256) {
        int r = idx / C, c = idx - r * C;
        int gr = rowbase + r;
        if (gr < n) out[(size_t)gr * C + c] = Hs[r * HP + c] - rowm[r] - rowls[r];
    }
}

extern "C" void kernel_launch(void* const* d_in, const int* in_sizes, int n_in,
                              void* d_out, int out_size, void* d_ws, size_t ws_size,
                              hipStream_t stream) {
    const float* x  = (const float*)d_in[0];
    const int*   ei = (const int*)d_in[1];
    const float* W1 = (const float*)d_in[2];
    const float* b1 = (const float*)d_in[3];
    const float* W2 = (const float*)d_in[4];
    const float* b2 = (const float*)d_in[5];
    float* out = (float*)d_out;

    const int n = in_sizes[0] / 128;   // 100000
    const int E = in_sizes[1] / 2;     // 800000
    const int* src = ei;
    const int* dst = ei + E;

    auto al = [](size_t x) { return (x + 255) & ~(size_t)255; };
    float* ws = (float*)d_ws;
    size_t o_deg  = 0;                          // n ints -> dinv floats in place
    size_t o_cnt  = al(n);                      // n ints (rowstart)
    size_t o_part = o_cnt + al(n);              // <=256 ints
    size_t o_rank = o_part + 1024;              // E ints
    size_t o_csr  = o_rank + al(E);             // E int2
    size_t o_h1   = o_csr + al((size_t)2 * E);  // n*64 halves (h1, later agg2)
    size_t o_out1 = o_h1 + al((size_t)n * 32);  // n*64 halves

    int*    degi     = (int*)(ws + o_deg);
    float*  dinv     = (float*)(ws + o_deg);
    int*    rowstart = (int*)(ws + o_cnt);
    int*    partial  = (int*)(ws + o_part);
    int*    rank     = (int*)(ws + o_rank);
    int2*   csr      = (int2*)(ws + o_csr);
    __half* h1       = (__half*)(ws + o_h1);
    __half* out1     = (__half*)(ws + o_out1);
    __half* agg2     = (__half*)(ws + o_h1);    // h1 dead after gather #1

    const int NB = (n + 1023) / 1024;

    zero_kernel<<<(n + 255) / 256, 256, 0, stream>>>(degi, n);
    deg_rank_kernel<<<(E + 255) / 256, 256, 0, stream>>>(dst, degi, rank, E);
    blocksum_kernel<<<NB, 256, 0, stream>>>(degi, partial, n);
    offsets_kernel<<<NB, 256, 0, stream>>>(degi, partial, rowstart, n, NB);
    fill_kernel<<<(E + 255) / 256, 256, 0, stream>>>(src, dst, rank, dinv, rowstart, csr, E);

    gemm1_mfma<<<(n + 63) / 64, 256, 0, stream>>>(x, W1, (_Float16*)h1, n);
    gather64h_kernel<true, true><<<((size_t)n * 8 + 255) / 256, 256, 0, stream>>>(
        h1, csr, rowstart, dinv, b1, out1, n, E);
    gather64h_kernel<false, false><<<((size_t)n * 8 + 255) / 256, 256, 0, stream>>>(
        out1, csr, rowstart, dinv, nullptr, agg2, n, E);
    gemm2_softmax_kernel<<<(n + 95) / 96, 256, 0, stream>>>(agg2, W2, b2, out, n);
}

// Round 11
// 137.438 us; speedup vs baseline: 1.3999x; 1.0491x over previous
//
#include <hip/hip_runtime.h>
#include <hip/hip_fp16.h>
#include <math.h>

// ---------------------------------------------------------------------------
// GCN 2-layer, CSR-gather formulation, fp16 intermediate storage + fp16 math:
//   rank[e] = atomicAdd(degi[dst[e]],1)      (histogram + rank in one pass)
//   rowstart = exscan(degi); dinv = rsqrt(degi+1)
//   csr[rowstart[t] + rank[e]] = (src, half2(nrm,nrm))    (atomic-free fill)
//   h1(fp16) = x @ W1   -- MFMA 16x16x32_f16, A-frags direct from global
//   out1(fp16) = relu(gather(h1) + self + b1)
//   out = log_softmax((gather(out1)+self) @ W2 + b2)  -- gather fused into GEMM2
// Gather shape: 8 lanes/node (one 128B row), no cross-lane reduction.
// ---------------------------------------------------------------------------

typedef _Float16 f16x8 __attribute__((ext_vector_type(8)));
typedef float    f32x4 __attribute__((ext_vector_type(4)));

__global__ void zero_kernel(int* __restrict__ p, int n) {
    int i = blockIdx.x * blockDim.x + threadIdx.x;
    if (i < n) p[i] = 0;
}

__global__ void deg_rank_kernel(const int* __restrict__ dst, int* __restrict__ degi,
                                int* __restrict__ rank, int E) {
    int i = blockIdx.x * blockDim.x + threadIdx.x;
    if (i < E) rank[i] = atomicAdd(&degi[dst[i]], 1);
}

// ---- block sums of degi (1024 items / block) ----
__global__ __launch_bounds__(256) void blocksum_kernel(const int* __restrict__ degi,
                                                       int* __restrict__ partial, int n) {
    __shared__ int sm[256];
    int t = threadIdx.x;
    int base = blockIdx.x * 1024 + t * 4;
    int s = 0;
#pragma unroll
    for (int j = 0; j < 4; ++j) { int i = base + j; if (i < n) s += degi[i]; }
    sm[t] = s;
    __syncthreads();
    for (int off = 128; off > 0; off >>= 1) {
        if (t < off) sm[t] += sm[t + off];
        __syncthreads();
    }
    if (t == 0) partial[blockIdx.x] = sm[0];
}

// rowstart = exscan(degi); partial-scan fused; degi <- rsqrt(degi+1) in place
__global__ __launch_bounds__(256) void offsets_kernel(int* __restrict__ degi,
                                                      const int* __restrict__ partial,
                                                      int* __restrict__ rowstart,
                                                      int n, int nb) {
    __shared__ int sm[256];
    __shared__ int pbase_s;
    int t = threadIdx.x;
    int pv = (t < nb) ? partial[t] : 0;
    sm[t] = pv;
    __syncthreads();
    for (int off = 1; off < 256; off <<= 1) {
        int x = (t >= off) ? sm[t - off] : 0;
        __syncthreads();
        sm[t] += x;
        __syncthreads();
    }
    if (t == 0) pbase_s = (blockIdx.x > 0) ? sm[blockIdx.x - 1] : 0;
    __syncthreads();
    int pbase = pbase_s;
    __syncthreads();   // sm about to be reused

    int base = blockIdx.x * 1024 + t * 4;
    int v[4]; int s = 0;
#pragma unroll
    for (int j = 0; j < 4; ++j) { v[j] = (base + j < n) ? degi[base + j] : 0; s += v[j]; }
    sm[t] = s;
    __syncthreads();
    for (int off = 1; off < 256; off <<= 1) {
        int x = (t >= off) ? sm[t - off] : 0;
        __syncthreads();
        sm[t] += x;
        __syncthreads();
    }
    int run = pbase + (sm[t] - s);
#pragma unroll
    for (int j = 0; j < 4; ++j) {
        if (base + j < n) {
            rowstart[base + j] = run; run += v[j];
            ((float*)degi)[base + j] = rsqrtf((float)v[j] + 1.0f);  // +1 self-loop
        }
    }
}

// atomic-free fill: pos = rowstart[t] + rank[e]; norm packed as half2
__global__ void fill_kernel(const int* __restrict__ src, const int* __restrict__ dst,
                            const int* __restrict__ rank, const float* __restrict__ dinv,
                            const int* __restrict__ rowstart, int2* __restrict__ csr, int E) {
    int e = blockIdx.x * blockDim.x + threadIdx.x;
    if (e >= E) return;
    int s = src[e], t = dst[e];
    float nrm = dinv[s] * dinv[t];
    unsigned short us = __half_as_ushort(__float2half_rn(nrm));
    int packed = (int)(((unsigned)us << 16) | us);
    int pos = rowstart[t] + rank[e];
    csr[pos] = make_int2(s, packed);
}

// ---- GEMM1 via MFMA: H[n,64](fp16) = X[n,128](fp32->fp16) @ W[128,64] ----
// 64 rows/block, 4 waves. A-fragments read DIRECTLY from global (X read once);
// W transposed+swizzled in LDS (16KB). Wave w owns rows 16w..16w+15.
__global__ __launch_bounds__(256) void gemm1_mfma(const float* __restrict__ X,
                                                  const float* __restrict__ W,
                                                  _Float16* __restrict__ H, int n) {
    __shared__ _Float16 Ws[64 * 128];   // [nn][k] (W transposed), swizzled
    int t = threadIdx.x;
    int rowbase = blockIdx.x * 64;

    // stage W transposed: W[k][nn] (row-major 128x64) -> Ws[nn][k]
    for (int i = t; i < 2048; i += 256) {
        int k = i >> 4;                   // 16 float4 per 64-float W row
        int nn0 = (i & 15) * 4;
        float4 v = *reinterpret_cast<const float4*>(W + (size_t)k * 64 + nn0);
        const float* vp = reinterpret_cast<const float*>(&v);
#pragma unroll
        for (int j = 0; j < 4; ++j) {
            int nn = nn0 + j;
            Ws[nn * 128 + (k ^ ((nn & 7) << 3))] = (_Float16)vp[j];
        }
    }

    int w = t >> 6;             // wave 0..3
    int l = t & 63;
    int lr = l & 15;            // row-within-tile for A / col for B,D
    int lk = l >> 4;            // k-subchunk 0..3
    int arow = rowbase + 16 * w + lr;
    int ar = arow < n ? arow : n - 1;

    // A-frags straight from global: 8 contiguous fp32 at k = kc*32 + lk*8
    f16x8 a[4];
#pragma unroll
    for (int kc = 0; kc < 4; ++kc) {
        const float* xp = X + (size_t)ar * 128 + kc * 32 + lk * 8;
        float4 v0 = *reinterpret_cast<const float4*>(xp);
        float4 v1 = *reinterpret_cast<const float4*>(xp + 4);
        f16x8 hv = { (_Float16)v0.x, (_Float16)v0.y, (_Float16)v0.z, (_Float16)v0.w,
                     (_Float16)v1.x, (_Float16)v1.y, (_Float16)v1.z, (_Float16)v1.w };
        a[kc] = hv;
    }
    __syncthreads();

    f32x4 acc[4] = {};
#pragma unroll
    for (int nt = 0; nt < 4; ++nt) {
        int nrow = 16 * nt + lr;
#pragma unroll
        for (int kc = 0; kc < 4; ++kc) {
            int k8 = kc * 32 + lk * 8;
            f16x8 b = *reinterpret_cast<f16x8*>(&Ws[nrow * 128 + (k8 ^ ((nrow & 7) << 3))]);
            acc[nt] = __builtin_amdgcn_mfma_f32_16x16x32_f16(a[kc], b, acc[nt], 0, 0, 0);
        }
    }
    // D: col = lane&15, row = (lane>>4)*4 + reg  [m89-verified]
#pragma unroll
    for (int nt = 0; nt < 4; ++nt) {
#pragma unroll
        for (int r = 0; r < 4; ++r) {
            int grow = rowbase + 16 * w + lk * 4 + r;
            if (grow < n) H[(size_t)grow * 64 + nt * 16 + lr] = (_Float16)acc[nt][r];
        }
    }
}

// branch-free half2 ReLU (sign-mask bit trick; avoids __hmax2 overload issues)
static __device__ __forceinline__ __half2 relu_h2(__half2 v) {
    unsigned u = *reinterpret_cast<unsigned*>(&v);
    unsigned neg = (u >> 15) & 0x00010001u;   // 1 per lane if sign bit set
    u &= ~(neg * 0xFFFFu);                    // zero negative lanes
    return *reinterpret_cast<__half2*>(&u);
}

// ---- gather over 64-feature fp16 rows: 8 lanes per node (one 128B row),
//      8 nodes per wave, 4 edges/node in flight, NO cross-lane reduction.
template <bool RELU, bool BIAS>
__global__ __launch_bounds__(256) void gather64h_kernel(const __half* __restrict__ Hh,
                                                        const int2* __restrict__ csr,
                                                        const int* __restrict__ rowstart,
                                                        const float* __restrict__ dinv,
                                                        const float* __restrict__ b,
                                                        __half* __restrict__ Oh, int n, int E) {
    int gt = blockIdx.x * blockDim.x + threadIdx.x;
    int node = gt >> 3;
    if (node >= n) return;
    int fl = gt & 7;            // 16 B chunk (8 features) within the row
    const float4* H4 = reinterpret_cast<const float4*>(Hh);
    int rs = rowstart[node];
    int re = (node + 1 < n) ? rowstart[node + 1] : E;
    __half2 acc[4];
#pragma unroll
    for (int q = 0; q < 4; ++q) acc[q] = __float2half2_rn(0.0f);

    int e = rs;
    while (__any(e < re)) {
        int srcrow[4]; __half2 nh[4]; float4 raw[4];
#pragma unroll
        for (int u = 0; u < 4; ++u) {
            int ee = e + u;
            bool valid = ee < re;
            int2 c = csr[valid ? ee : rs];
            srcrow[u] = valid ? c.x : 0;
            int ni = valid ? c.y : 0;
            nh[u] = *reinterpret_cast<__half2*>(&ni);
        }
#pragma unroll
        for (int u = 0; u < 4; ++u)
            raw[u] = H4[srcrow[u] * 8 + fl];
#pragma unroll
        for (int u = 0; u < 4; ++u) {
            const __half2* hp = reinterpret_cast<const __half2*>(&raw[u]);
#pragma unroll
            for (int q = 0; q < 4; ++q)
                acc[q] = __hfma2(hp[q], nh[u], acc[q]);
        }
        e += 4;
    }
    // self-loop
    {
        float di = dinv[node];
        __half2 d2 = __float2half2_rn(di * di);
        float4 raw = H4[node * 8 + fl];
        const __half2* hp = reinterpret_cast<const __half2*>(&raw);
#pragma unroll
        for (int q = 0; q < 4; ++q) acc[q] = __hfma2(hp[q], d2, acc[q]);
    }
    if (BIAS) {
        float4 b0 = reinterpret_cast<const float4*>(b)[fl * 2];
        float4 b1 = reinterpret_cast<const float4*>(b)[fl * 2 + 1];
        acc[0] = __hadd2(acc[0], __float22half2_rn(make_float2(b0.x, b0.y)));
        acc[1] = __hadd2(acc[1], __float22half2_rn(make_float2(b0.z, b0.w)));
        acc[2] = __hadd2(acc[2], __float22half2_rn(make_float2(b1.x, b1.y)));
        acc[3] = __hadd2(acc[3], __float22half2_rn(make_float2(b1.z, b1.w)));
    }
    if (RELU) {
#pragma unroll
        for (int q = 0; q < 4; ++q) acc[q] = relu_h2(acc[q]);
    }
    float4 o;
    __half2* op = reinterpret_cast<__half2*>(&o);
#pragma unroll
    for (int q = 0; q < 4; ++q) op[q] = acc[q];
    *reinterpret_cast<float4*>(Oh + (size_t)node * 64 + fl * 8) = o;
}

// ---- FUSED: agg2 = gather(out1)+self (into LDS, fp32), then
//      out = log_softmax(agg2 @ W2 + b2).  64 nodes per block.
__global__ __launch_bounds__(256) void gather_gemm2_softmax(
        const __half* __restrict__ Hh, const int2* __restrict__ csr,
        const int* __restrict__ rowstart, const float* __restrict__ dinv,
        const float* __restrict__ W, const float* __restrict__ b,
        float* __restrict__ out, int n, int E) {
    constexpr int BM = 64, K = 64, C = 40, XP = 68, HP = 41;
    __shared__ float Xs[BM * XP];     // gathered agg2 rows; reused as Hs[64][41]
    __shared__ float Ws[K * C];
    __shared__ float bs[C];
    __shared__ float rowm[BM], rowls[BM];
    int t = threadIdx.x;
    int rowbase = blockIdx.x * BM;

    for (int i = t; i < K * C / 4; i += 256)
        ((float4*)Ws)[i] = ((const float4*)W)[i];
    if (t < C) bs[t] = b[t];

    // ---- gather phase: 32 teams of 8 lanes; 2 passes cover 64 nodes ----
    int team = t >> 3, fl = t & 7;
    const float4* H4 = reinterpret_cast<const float4*>(Hh);
#pragma unroll
    for (int pass = 0; pass < 2; ++pass) {
        int lrow = team + pass * 32;       // local row 0..63
        int node = rowbase + lrow;
        __half2 acc[4];
#pragma unroll
        for (int q = 0; q < 4; ++q) acc[q] = __float2half2_rn(0.0f);
        if (node < n) {
            int rs = rowstart[node];
            int re = (node + 1 < n) ? rowstart[node + 1] : E;
            int e = rs;
            while (__any(e < re)) {
                int srcrow[4]; __half2 nh[4]; float4 raw[4];
#pragma unroll
                for (int u = 0; u < 4; ++u) {
                    int ee = e + u;
                    bool valid = ee < re;
                    int2 c = csr[valid ? ee : rs];
                    srcrow[u] = valid ? c.x : 0;
                    int ni = valid ? c.y : 0;
                    nh[u] = *reinterpret_cast<__half2*>(&ni);
                }
#pragma unroll
                for (int u = 0; u < 4; ++u)
                    raw[u] = H4[srcrow[u] * 8 + fl];
#pragma unroll
                for (int u = 0; u < 4; ++u) {
                    const __half2* hp = reinterpret_cast<const __half2*>(&raw[u]);
#pragma unroll
                    for (int q = 0; q < 4; ++q)
                        acc[q] = __hfma2(hp[q], nh[u], acc[q]);
                }
                e += 4;
            }
            // self-loop
            float di = dinv[node];
            __half2 d2 = __float2half2_rn(di * di);
            float4 raw = H4[node * 8 + fl];
            const __half2* hp = reinterpret_cast<const __half2*>(&raw);
#pragma unroll
            for (int q = 0; q < 4; ++q) acc[q] = __hfma2(hp[q], d2, acc[q]);
        }
        // write 8 fp32 features into the GEMM X-tile
        float* dp = &Xs[lrow * XP + fl * 8];
        float2 f0 = __half22float2(acc[0]), f1 = __half22float2(acc[1]);
        float2 f2 = __half22float2(acc[2]), f3 = __half22float2(acc[3]);
        *reinterpret_cast<float4*>(dp)     = make_float4(f0.x, f0.y, f1.x, f1.y);
        *reinterpret_cast<float4*>(dp + 4) = make_float4(f2.x, f2.y, f3.x, f3.y);
    }
    __syncthreads();

    // ---- GEMM phase: 16 row-groups x 10 col-groups = 160 active threads ----
    int tx = t % (C / 4);             // 0..9
    int ty = t / (C / 4);             // 0..25
    bool active = ty < BM / 4;        // ty < 16
    float acc[4][4] = {};
    if (active) {
#pragma unroll
        for (int k0 = 0; k0 < K; k0 += 4) {
            float4 xq[4], wq[4];
#pragma unroll
            for (int i = 0; i < 4; ++i)
                xq[i] = *reinterpret_cast<const float4*>(&Xs[(ty * 4 + i) * XP + k0]);
#pragma unroll
            for (int j = 0; j < 4; ++j)
                wq[j] = *reinterpret_cast<const float4*>(&Ws[(k0 + j) * C + tx * 4]);
#pragma unroll
            for (int i = 0; i < 4; ++i) {
                const float* xa = reinterpret_cast<const float*>(&xq[i]);
#pragma unroll
                for (int j = 0; j < 4; ++j) {
                    const float* wb = reinterpret_cast<const float*>(&wq[j]);
                    acc[i][0] += xa[j] * wb[0];
                    acc[i][1] += xa[j] * wb[1];
                    acc[i][2] += xa[j] * wb[2];
                    acc[i][3] += xa[j] * wb[3];
                }
            }
        }
    }
    __syncthreads();                  // everyone done reading Xs
    float* Hs = Xs;                   // reuse as [BM][41]
    if (active) {
#pragma unroll
        for (int i = 0; i < 4; ++i) {
            int r = ty * 4 + i;
#pragma unroll
            for (int j = 0; j < 4; ++j)
                Hs[r * HP + tx * 4 + j] = acc[i][j] + bs[tx * 4 + j];
        }
    }
    __syncthreads();
    if (t < BM) {
        float m = -INFINITY;
        for (int j = 0; j < C; ++j) m = fmaxf(m, Hs[t * HP + j]);
        float s = 0.f;
        for (int j = 0; j < C; ++j) s += __expf(Hs[t * HP + j] - m);
        rowm[t] = m; rowls[t] = __logf(s);
    }
    __syncthreads();
    for (int idx = t; idx < BM * C; idx += 256) {
        int r = idx / C, c = idx - r * C;
        int gr = rowbase + r;
        if (gr < n) out[(size_t)gr * C + c] = Hs[r * HP + c] - rowm[r] - rowls[r];
    }
}

extern "C" void kernel_launch(void* const* d_in, const int* in_sizes, int n_in,
                              void* d_out, int out_size, void* d_ws, size_t ws_size,
                              hipStream_t stream) {
    const float* x  = (const float*)d_in[0];
    const int*   ei = (const int*)d_in[1];
    const float* W1 = (const float*)d_in[2];
    const float* b1 = (const float*)d_in[3];
    const float* W2 = (const float*)d_in[4];
    const float* b2 = (const float*)d_in[5];
    float* out = (float*)d_out;

    const int n = in_sizes[0] / 128;   // 100000
    const int E = in_sizes[1] / 2;     // 800000
    const int* src = ei;
    const int* dst = ei + E;

    auto al = [](size_t x) { return (x + 255) & ~(size_t)255; };
    float* ws = (float*)d_ws;
    size_t o_deg  = 0;                          // n ints -> dinv floats in place
    size_t o_cnt  = al(n);                      // n ints (rowstart)
    size_t o_part = o_cnt + al(n);              // <=256 ints
    size_t o_rank = o_part + 1024;              // E ints
    size_t o_csr  = o_rank + al(E);             // E int2
    size_t o_h1   = o_csr + al((size_t)2 * E);  // n*64 halves
    size_t o_out1 = o_h1 + al((size_t)n * 32);  // n*64 halves

    int*    degi     = (int*)(ws + o_deg);
    float*  dinv     = (float*)(ws + o_deg);
    int*    rowstart = (int*)(ws + o_cnt);
    int*    partial  = (int*)(ws + o_part);
    int*    rank     = (int*)(ws + o_rank);
    int2*   csr      = (int2*)(ws + o_csr);
    __half* h1       = (__half*)(ws + o_h1);
    __half* out1     = (__half*)(ws + o_out1);

    const int NB = (n + 1023) / 1024;

    zero_kernel<<<(n + 255) / 256, 256, 0, stream>>>(degi, n);
    deg_rank_kernel<<<(E + 255) / 256, 256, 0, stream>>>(dst, degi, rank, E);
    blocksum_kernel<<<NB, 256, 0, stream>>>(degi, partial, n);
    offsets_kernel<<<NB, 256, 0, stream>>>(degi, partial, rowstart, n, NB);
    fill_kernel<<<(E + 255) / 256, 256, 0, stream>>>(src, dst, rank, dinv, rowstart, csr, E);

    gemm1_mfma<<<(n + 63) / 64, 256, 0, stream>>>(x, W1, (_Float16*)h1, n);
    gather64h_kernel<true, true><<<((size_t)n * 8 + 255) / 256, 256, 0, stream>>>(
        h1, csr, rowstart, dinv, b1, out1, n, E);
    gather_gemm2_softmax<<<(n + 63) / 64, 256, 0, stream>>>(
        out1, csr, rowstart, dinv, W2, b2, out, n, E);
}

// Round 12
// 135.553 us; speedup vs baseline: 1.4194x; 1.0139x over previous
//
#include <hip/hip_runtime.h>
#include <hip/hip_fp16.h>
#include <math.h>

// ---------------------------------------------------------------------------
// GCN 2-layer, CSR-gather formulation, fp16 intermediate storage + fp16 math:
//   rank[e] = atomicAdd(degi[dst[e]],1)   (histogram+rank, OVERLAPPED w/ gemm1 A)
//   rowstart = exscan(degi); dinv = rsqrt(degi+1)
//   csr[rowstart[t]+rank[e]] = (src, half2(nrm))  (fill, OVERLAPPED w/ gemm1 B)
//   h1(fp16) = x @ W1   -- MFMA 16x16x32_f16, A-frags direct from global
//   out1(fp16) = relu(gather(h1) + self + b1)
//   out = log_softmax((gather(out1)+self) @ W2 + b2)  -- gather fused into GEMM2
// ---------------------------------------------------------------------------

typedef _Float16 f16x8 __attribute__((ext_vector_type(8)));
typedef float    f32x4 __attribute__((ext_vector_type(4)));

__global__ void zero_kernel(int* __restrict__ p, int n) {
    int i = blockIdx.x * blockDim.x + threadIdx.x;
    if (i < n) p[i] = 0;
}

// ---- gemm1 tile body: H[tile*64 .. +64, 0..64](fp16) = X @ W1, MFMA ----
static __device__ __forceinline__ void gemm1_tile(const float* __restrict__ X,
                                                  const float* __restrict__ W,
                                                  _Float16* __restrict__ H, int n,
                                                  int tile, _Float16* Ws /*64*128 LDS*/) {
    int t = threadIdx.x;
    int rowbase = tile * 64;

    // stage W transposed: W[k][nn] (row-major 128x64) -> Ws[nn][k], swizzled
    for (int i = t; i < 2048; i += 256) {
        int k = i >> 4;
        int nn0 = (i & 15) * 4;
        float4 v = *reinterpret_cast<const float4*>(W + (size_t)k * 64 + nn0);
        const float* vp = reinterpret_cast<const float*>(&v);
#pragma unroll
        for (int j = 0; j < 4; ++j) {
            int nn = nn0 + j;
            Ws[nn * 128 + (k ^ ((nn & 7) << 3))] = (_Float16)vp[j];
        }
    }

    int w = t >> 6;
    int l = t & 63;
    int lr = l & 15;
    int lk = l >> 4;
    int arow = rowbase + 16 * w + lr;
    int ar = arow < n ? arow : n - 1;

    f16x8 a[4];
#pragma unroll
    for (int kc = 0; kc < 4; ++kc) {
        const float* xp = X + (size_t)ar * 128 + kc * 32 + lk * 8;
        float4 v0 = *reinterpret_cast<const float4*>(xp);
        float4 v1 = *reinterpret_cast<const float4*>(xp + 4);
        f16x8 hv = { (_Float16)v0.x, (_Float16)v0.y, (_Float16)v0.z, (_Float16)v0.w,
                     (_Float16)v1.x, (_Float16)v1.y, (_Float16)v1.z, (_Float16)v1.w };
        a[kc] = hv;
    }
    __syncthreads();

    f32x4 acc[4] = {};
#pragma unroll
    for (int nt = 0; nt < 4; ++nt) {
        int nrow = 16 * nt + lr;
#pragma unroll
        for (int kc = 0; kc < 4; ++kc) {
            int k8 = kc * 32 + lk * 8;
            f16x8 b = *reinterpret_cast<f16x8*>(&Ws[nrow * 128 + (k8 ^ ((nrow & 7) << 3))]);
            acc[nt] = __builtin_amdgcn_mfma_f32_16x16x32_f16(a[kc], b, acc[nt], 0, 0, 0);
        }
    }
    // D: col = lane&15, row = (lane>>4)*4 + reg
#pragma unroll
    for (int nt = 0; nt < 4; ++nt) {
#pragma unroll
        for (int r = 0; r < 4; ++r) {
            int grow = rowbase + 16 * w + lk * 4 + r;
            if (grow < n) H[(size_t)grow * 64 + nt * 16 + lr] = (_Float16)acc[nt][r];
        }
    }
}

// ---- FAT K2: deg_rank (blocks < nDeg)  ∥  gemm1 tiles [0, tilesA) ----
__global__ __launch_bounds__(256) void degrank_gemm1_kernel(
        const int* __restrict__ dst, int* __restrict__ degi, int* __restrict__ rank, int E,
        const float* __restrict__ X, const float* __restrict__ W,
        _Float16* __restrict__ H, int n, int nDeg) {
    __shared__ _Float16 Ws[64 * 128];
    int b = blockIdx.x;
    if (b < nDeg) {
        int i = b * 256 + threadIdx.x;
        if (i < E) rank[i] = atomicAdd(&degi[dst[i]], 1);
    } else {
        gemm1_tile(X, W, H, n, b - nDeg, Ws);
    }
}

// ---- FAT K5: fill (blocks < nFill)  ∥  gemm1 tiles [tilesA, ntiles) ----
__global__ __launch_bounds__(256) void fill_gemm1_kernel(
        const int* __restrict__ src, const int* __restrict__ dst,
        const int* __restrict__ rank, const float* __restrict__ dinv,
        const int* __restrict__ rowstart, int2* __restrict__ csr, int E,
        const float* __restrict__ X, const float* __restrict__ W,
        _Float16* __restrict__ H, int n, int nFill, int tileOff) {
    __shared__ _Float16 Ws[64 * 128];
    int b = blockIdx.x;
    if (b < nFill) {
        int e = b * 256 + threadIdx.x;
        if (e >= E) return;
        int s = src[e], t = dst[e];
        float nrm = dinv[s] * dinv[t];
        unsigned short us = __half_as_ushort(__float2half_rn(nrm));
        int packed = (int)(((unsigned)us << 16) | us);
        int pos = rowstart[t] + rank[e];
        csr[pos] = make_int2(s, packed);
    } else {
        gemm1_tile(X, W, H, n, b - nFill + tileOff, Ws);
    }
}

// ---- block sums of degi (1024 items / block) ----
__global__ __launch_bounds__(256) void blocksum_kernel(const int* __restrict__ degi,
                                                       int* __restrict__ partial, int n) {
    __shared__ int sm[256];
    int t = threadIdx.x;
    int base = blockIdx.x * 1024 + t * 4;
    int s = 0;
#pragma unroll
    for (int j = 0; j < 4; ++j) { int i = base + j; if (i < n) s += degi[i]; }
    sm[t] = s;
    __syncthreads();
    for (int off = 128; off > 0; off >>= 1) {
        if (t < off) sm[t] += sm[t + off];
        __syncthreads();
    }
    if (t == 0) partial[blockIdx.x] = sm[0];
}

// rowstart = exscan(degi); partial-scan fused; degi <- rsqrt(degi+1) in place
__global__ __launch_bounds__(256) void offsets_kernel(int* __restrict__ degi,
                                                      const int* __restrict__ partial,
                                                      int* __restrict__ rowstart,
                                                      int n, int nb) {
    __shared__ int sm[256];
    __shared__ int pbase_s;
    int t = threadIdx.x;
    int pv = (t < nb) ? partial[t] : 0;
    sm[t] = pv;
    __syncthreads();
    for (int off = 1; off < 256; off <<= 1) {
        int x = (t >= off) ? sm[t - off] : 0;
        __syncthreads();
        sm[t] += x;
        __syncthreads();
    }
    if (t == 0) pbase_s = (blockIdx.x > 0) ? sm[blockIdx.x - 1] : 0;
    __syncthreads();
    int pbase = pbase_s;
    __syncthreads();   // sm about to be reused

    int base = blockIdx.x * 1024 + t * 4;
    int v[4]; int s = 0;
#pragma unroll
    for (int j = 0; j < 4; ++j) { v[j] = (base + j < n) ? degi[base + j] : 0; s += v[j]; }
    sm[t] = s;
    __syncthreads();
    for (int off = 1; off < 256; off <<= 1) {
        int x = (t >= off) ? sm[t - off] : 0;
        __syncthreads();
        sm[t] += x;
        __syncthreads();
    }
    int run = pbase + (sm[t] - s);
#pragma unroll
    for (int j = 0; j < 4; ++j) {
        if (base + j < n) {
            rowstart[base + j] = run; run += v[j];
            ((float*)degi)[base + j] = rsqrtf((float)v[j] + 1.0f);  // +1 self-loop
        }
    }
}

// branch-free half2 ReLU (sign-mask bit trick; avoids __hmax2 overload issues)
static __device__ __forceinline__ __half2 relu_h2(__half2 v) {
    unsigned u = *reinterpret_cast<unsigned*>(&v);
    unsigned neg = (u >> 15) & 0x00010001u;
    u &= ~(neg * 0xFFFFu);
    return *reinterpret_cast<__half2*>(&u);
}

// ---- gather over 64-feature fp16 rows: 8 lanes per node (one 128B row),
//      8 nodes per wave, 4 edges/node in flight, NO cross-lane reduction.
template <bool RELU, bool BIAS>
__global__ __launch_bounds__(256) void gather64h_kernel(const __half* __restrict__ Hh,
                                                        const int2* __restrict__ csr,
                                                        const int* __restrict__ rowstart,
                                                        const float* __restrict__ dinv,
                                                        const float* __restrict__ b,
                                                        __half* __restrict__ Oh, int n, int E) {
    int gt = blockIdx.x * blockDim.x + threadIdx.x;
    int node = gt >> 3;
    if (node >= n) return;
    int fl = gt & 7;
    const float4* H4 = reinterpret_cast<const float4*>(Hh);
    int rs = rowstart[node];
    int re = (node + 1 < n) ? rowstart[node + 1] : E;
    __half2 acc[4];
#pragma unroll
    for (int q = 0; q < 4; ++q) acc[q] = __float2half2_rn(0.0f);

    int e = rs;
    while (__any(e < re)) {
        int srcrow[4]; __half2 nh[4]; float4 raw[4];
#pragma unroll
        for (int u = 0; u < 4; ++u) {
            int ee = e + u;
            bool valid = ee < re;
            int2 c = csr[valid ? ee : rs];
            srcrow[u] = valid ? c.x : 0;
            int ni = valid ? c.y : 0;
            nh[u] = *reinterpret_cast<__half2*>(&ni);
        }
#pragma unroll
        for (int u = 0; u < 4; ++u)
            raw[u] = H4[srcrow[u] * 8 + fl];
#pragma unroll
        for (int u = 0; u < 4; ++u) {
            const __half2* hp = reinterpret_cast<const __half2*>(&raw[u]);
#pragma unroll
            for (int q = 0; q < 4; ++q)
                acc[q] = __hfma2(hp[q], nh[u], acc[q]);
        }
        e += 4;
    }
    // self-loop
    {
        float di = dinv[node];
        __half2 d2 = __float2half2_rn(di * di);
        float4 raw = H4[node * 8 + fl];
        const __half2* hp = reinterpret_cast<const __half2*>(&raw);
#pragma unroll
        for (int q = 0; q < 4; ++q) acc[q] = __hfma2(hp[q], d2, acc[q]);
    }
    if (BIAS) {
        float4 b0 = reinterpret_cast<const float4*>(b)[fl * 2];
        float4 b1 = reinterpret_cast<const float4*>(b)[fl * 2 + 1];
        acc[0] = __hadd2(acc[0], __float22half2_rn(make_float2(b0.x, b0.y)));
        acc[1] = __hadd2(acc[1], __float22half2_rn(make_float2(b0.z, b0.w)));
        acc[2] = __hadd2(acc[2], __float22half2_rn(make_float2(b1.x, b1.y)));
        acc[3] = __hadd2(acc[3], __float22half2_rn(make_float2(b1.z, b1.w)));
    }
    if (RELU) {
#pragma unroll
        for (int q = 0; q < 4; ++q) acc[q] = relu_h2(acc[q]);
    }
    float4 o;
    __half2* op = reinterpret_cast<__half2*>(&o);
#pragma unroll
    for (int q = 0; q < 4; ++q) op[q] = acc[q];
    *reinterpret_cast<float4*>(Oh + (size_t)node * 64 + fl * 8) = o;
}

// ---- FUSED: agg2 = gather(out1)+self (into LDS, fp32), then
//      out = log_softmax(agg2 @ W2 + b2).  64 nodes per block.
__global__ __launch_bounds__(256) void gather_gemm2_softmax(
        const __half* __restrict__ Hh, const int2* __restrict__ csr,
        const int* __restrict__ rowstart, const float* __restrict__ dinv,
        const float* __restrict__ W, const float* __restrict__ b,
        float* __restrict__ out, int n, int E) {
    constexpr int BM = 64, K = 64, C = 40, XP = 68, HP = 41;
    __shared__ float Xs[BM * XP];
    __shared__ float Ws[K * C];
    __shared__ float bs[C];
    __shared__ float rowm[BM], rowls[BM];
    int t = threadIdx.x;
    int rowbase = blockIdx.x * BM;

    for (int i = t; i < K * C / 4; i += 256)
        ((float4*)Ws)[i] = ((const float4*)W)[i];
    if (t < C) bs[t] = b[t];

    int team = t >> 3, fl = t & 7;
    const float4* H4 = reinterpret_cast<const float4*>(Hh);
#pragma unroll
    for (int pass = 0; pass < 2; ++pass) {
        int lrow = team + pass * 32;
        int node = rowbase + lrow;
        __half2 acc[4];
#pragma unroll
        for (int q = 0; q < 4; ++q) acc[q] = __float2half2_rn(0.0f);
        if (node < n) {
            int rs = rowstart[node];
            int re = (node + 1 < n) ? rowstart[node + 1] : E;
            int e = rs;
            while (__any(e < re)) {
                int srcrow[4]; __half2 nh[4]; float4 raw[4];
#pragma unroll
                for (int u = 0; u < 4; ++u) {
                    int ee = e + u;
                    bool valid = ee < re;
                    int2 c = csr[valid ? ee : rs];
                    srcrow[u] = valid ? c.x : 0;
                    int ni = valid ? c.y : 0;
                    nh[u] = *reinterpret_cast<__half2*>(&ni);
                }
#pragma unroll
                for (int u = 0; u < 4; ++u)
                    raw[u] = H4[srcrow[u] * 8 + fl];
#pragma unroll
                for (int u = 0; u < 4; ++u) {
                    const __half2* hp = reinterpret_cast<const __half2*>(&raw[u]);
#pragma unroll
                    for (int q = 0; q < 4; ++q)
                        acc[q] = __hfma2(hp[q], nh[u], acc[q]);
                }
                e += 4;
            }
            float di = dinv[node];
            __half2 d2 = __float2half2_rn(di * di);
            float4 raw = H4[node * 8 + fl];
            const __half2* hp = reinterpret_cast<const __half2*>(&raw);
#pragma unroll
            for (int q = 0; q < 4; ++q) acc[q] = __hfma2(hp[q], d2, acc[q]);
        }
        float* dp = &Xs[lrow * XP + fl * 8];
        float2 f0 = __half22float2(acc[0]), f1 = __half22float2(acc[1]);
        float2 f2 = __half22float2(acc[2]), f3 = __half22float2(acc[3]);
        *reinterpret_cast<float4*>(dp)     = make_float4(f0.x, f0.y, f1.x, f1.y);
        *reinterpret_cast<float4*>(dp + 4) = make_float4(f2.x, f2.y, f3.x, f3.y);
    }
    __syncthreads();

    int tx = t % (C / 4);
    int ty = t / (C / 4);
    bool active = ty < BM / 4;
    float acc[4][4] = {};
    if (active) {
#pragma unroll
        for (int k0 = 0; k0 < K; k0 += 4) {
            float4 xq[4], wq[4];
#pragma unroll
            for (int i = 0; i < 4; ++i)
                xq[i] = *reinterpret_cast<const float4*>(&Xs[(ty * 4 + i) * XP + k0]);
#pragma unroll
            for (int j = 0; j < 4; ++j)
                wq[j] = *reinterpret_cast<const float4*>(&Ws[(k0 + j) * C + tx * 4]);
#pragma unroll
            for (int i = 0; i < 4; ++i) {
                const float* xa = reinterpret_cast<const float*>(&xq[i]);
#pragma unroll
                for (int j = 0; j < 4; ++j) {
                    const float* wb = reinterpret_cast<const float*>(&wq[j]);
                    acc[i][0] += xa[j] * wb[0];
                    acc[i][1] += xa[j] * wb[1];
                    acc[i][2] += xa[j] * wb[2];
                    acc[i][3] += xa[j] * wb[3];
                }
            }
        }
    }
    __syncthreads();
    float* Hs = Xs;
    if (active) {
#pragma unroll
        for (int i = 0; i < 4; ++i) {
            int r = ty * 4 + i;
#pragma unroll
            for (int j = 0; j < 4; ++j)
                Hs[r * HP + tx * 4 + j] = acc[i][j] + bs[tx * 4 + j];
        }
    }
    __syncthreads();
    if (t < BM) {
        float m = -INFINITY;
        for (int j = 0; j < C; ++j) m = fmaxf(m, Hs[t * HP + j]);
        float s = 0.f;
        for (int j = 0; j < C; ++j) s += __expf(Hs[t * HP + j] - m);
        rowm[t] = m; rowls[t] = __logf(s);
    }
    __syncthreads();
    for (int idx = t; idx < BM * C; idx += 256) {
        int r = idx / C, c = idx - r * C;
        int gr = rowbase + r;
        if (gr < n) out[(size_t)gr * C + c] = Hs[r * HP + c] - rowm[r] - rowls[r];
    }
}

extern "C" void kernel_launch(void* const* d_in, const int* in_sizes, int n_in,
                              void* d_out, int out_size, void* d_ws, size_t ws_size,
                              hipStream_t stream) {
    const float* x  = (const float*)d_in[0];
    const int*   ei = (const int*)d_in[1];
    const float* W1 = (const float*)d_in[2];
    const float* b1 = (const float*)d_in[3];
    const float* W2 = (const float*)d_in[4];
    const float* b2 = (const float*)d_in[5];
    float* out = (float*)d_out;

    const int n = in_sizes[0] / 128;   // 100000
    const int E = in_sizes[1] / 2;     // 800000
    const int* src = ei;
    const int* dst = ei + E;

    auto al = [](size_t x) { return (x + 255) & ~(size_t)255; };
    float* ws = (float*)d_ws;
    size_t o_deg  = 0;                          // n ints -> dinv floats in place
    size_t o_cnt  = al(n);                      // n ints (rowstart)
    size_t o_part = o_cnt + al(n);              // <=256 ints
    size_t o_rank = o_part + 1024;              // E ints
    size_t o_csr  = o_rank + al(E);             // E int2
    size_t o_h1   = o_csr + al((size_t)2 * E);  // n*64 halves
    size_t o_out1 = o_h1 + al((size_t)n * 32);  // n*64 halves

    int*    degi     = (int*)(ws + o_deg);
    float*  dinv     = (float*)(ws + o_deg);
    int*    rowstart = (int*)(ws + o_cnt);
    int*    partial  = (int*)(ws + o_part);
    int*    rank     = (int*)(ws + o_rank);
    int2*   csr      = (int2*)(ws + o_csr);
    __half* h1       = (__half*)(ws + o_h1);
    __half* out1     = (__half*)(ws + o_out1);

    const int NB = (n + 1023) / 1024;
    const int nDeg   = (E + 255) / 256;          // 3125
    const int ntiles = (n + 63) / 64;            // 1563
    const int tilesA = ntiles / 2;               // 781
    const int tilesB = ntiles - tilesA;          // 782

    zero_kernel<<<(n + 255) / 256, 256, 0, stream>>>(degi, n);
    degrank_gemm1_kernel<<<nDeg + tilesA, 256, 0, stream>>>(
        dst, degi, rank, E, x, W1, (_Float16*)h1, n, nDeg);
    blocksum_kernel<<<NB, 256, 0, stream>>>(degi, partial, n);
    offsets_kernel<<<NB, 256, 0, stream>>>(degi, partial, rowstart, n, NB);
    fill_gemm1_kernel<<<nDeg + tilesB, 256, 0, stream>>>(
        src, dst, rank, dinv, rowstart, csr, E, x, W1, (_Float16*)h1, n, nDeg, tilesA);
    gather64h_kernel<true, true><<<((size_t)n * 8 + 255) / 256, 256, 0, stream>>>(
        h1, csr, rowstart, dinv, b1, out1, n, E);
    gather_gemm2_softmax<<<(n + 63) / 64, 256, 0, stream>>>(
        out1, csr, rowstart, dinv, W2, b2, out, n, E);
}